// Round 2
// baseline (1016.881 us; speedup 1.0000x reference)
//
#include <hip/hip_runtime.h>
#include <cstdint>
#include <cstddef>

typedef unsigned short u16;
typedef __attribute__((ext_vector_type(8))) short bf16x8;   // 8 bf16 = 4 VGPRs
typedef __attribute__((ext_vector_type(4))) float f32x4;    // MFMA 16x16 C/D

using gas_ptr = const __attribute__((address_space(1))) void*;
using las_ptr = __attribute__((address_space(3))) void*;

__device__ __forceinline__ u16 f2bf(float f) {
  union { float f; unsigned int u; } v; v.f = f;
  unsigned int u = v.u;
  return (u16)((u + 0x7fffu + ((u >> 16) & 1u)) >> 16);  // RNE
}

__device__ __forceinline__ float fast_exp2(float x) {
  return __builtin_amdgcn_exp2f(x);   // raw v_exp_f32
}

// ---------------- elementwise fp32 -> bf16 convert (vectorized x4) ----------------
__global__ __launch_bounds__(256) void cvt_f32_bf16(const float* __restrict__ src,
                                                    u16* __restrict__ dst, int n) {
  int i = (blockIdx.x * 256 + threadIdx.x) * 4;
  if (i >= n) return;
  float4 v = *(const float4*)(src + i);
  ushort4 o;
  o.x = f2bf(v.x); o.y = f2bf(v.y); o.z = f2bf(v.z); o.w = f2bf(v.w);
  *(ushort4*)(dst + i) = o;
}

// ---------------- m97-style bf16 GEMM: C[M,N] = A[M,K] * B[N,K]^T (fp32 out) ------
// kept for the Wo GEMM (grid 32x16 = 512 blocks; a 256^2 tile would leave half the
// CUs idle at M=2048,N=4096).
__global__ __launch_bounds__(256) void gemm_bt(const u16* __restrict__ A,
                                               const u16* __restrict__ B,
                                               float* __restrict__ C,
                                               int M, int N, int K) {
  __shared__ u16 As[128][32];
  __shared__ u16 Bs[128][32];
  const int m0 = blockIdx.y * 128, n0 = blockIdx.x * 128;
  const int tid = threadIdx.x;
  const int wave = tid >> 6, lane = tid & 63;
  const int wm = (wave & 1) * 64, wn = (wave >> 1) * 64;
  const int srow = lane >> 2, skoff = (lane & 3) * 8;
  const int col = lane & 15, quad = lane >> 4;
  f32x4 acc[4][4] = {};
  for (int k0 = 0; k0 < K; k0 += 32) {
#pragma unroll
    for (int r = 0; r < 2; ++r) {
      const u16* ga = A + (size_t)(m0 + r * 64 + wave * 16 + srow) * K + k0 + skoff;
      const u16* gb = B + (size_t)(n0 + r * 64 + wave * 16 + srow) * K + k0 + skoff;
      __builtin_amdgcn_global_load_lds((gas_ptr)ga, (las_ptr)&As[r * 64 + wave * 16][0], 16, 0, 0);
      __builtin_amdgcn_global_load_lds((gas_ptr)gb, (las_ptr)&Bs[r * 64 + wave * 16][0], 16, 0, 0);
    }
    __syncthreads();
    bf16x8 af[4], bfr[4];
#pragma unroll
    for (int t = 0; t < 4; ++t) {
      af[t]  = *(const bf16x8*)&As[wm + t * 16 + col][quad * 8];
      bfr[t] = *(const bf16x8*)&Bs[wn + t * 16 + col][quad * 8];
    }
#pragma unroll
    for (int mt = 0; mt < 4; ++mt)
#pragma unroll
      for (int nt = 0; nt < 4; ++nt)
        acc[mt][nt] = __builtin_amdgcn_mfma_f32_16x16x32_bf16(af[mt], bfr[nt], acc[mt][nt], 0, 0, 0);
    __syncthreads();
  }
#pragma unroll
  for (int mt = 0; mt < 4; ++mt)
#pragma unroll
    for (int nt = 0; nt < 4; ++nt)
#pragma unroll
      for (int r = 0; r < 4; ++r) {
        const int row  = m0 + wm + mt * 16 + quad * 4 + r;
        const int ccol = n0 + wn + nt * 16 + col;
        C[(size_t)row * N + ccol] = acc[mt][nt][r];
      }
}

// ---------------- 256x256 8-phase bf16 GEMM (T2+T3+T4+T5), C = A[M,K] * B[N,K]^T --
// Round-1 fix: deepen the prefetch to the template's 3-half-tiles-in-flight /
// vmcnt(6). Every half-tile is now staged 6-7 phases before its consuming ds_read
// (issue->wait cover ~960cy >= ~900cy HBM-miss latency), vs 2-3 phases before.
// Stage stream (iter i computes tiles t=2i from buf0, t'=2i+1 from buf1):
//   ph1: t'.B1   ph2: (t+2).A0   ph3: (t+2).B0   ph4: (t+2).A1
//   ph5: (t+2).B1   ph6: (t+3).A0   ph7: (t+3).B0   ph8: (t+3).A1
// Slot-safety (write strictly after last-read phase; phase-ending barrier drains
// all waves' lgkm first): B1'@ph1>prev-ph7, A0@ph2>ph1, B0@ph3>ph1, A1@ph4>ph2,
// B1@ph5>ph3, A0'@ph6>ph5, B0'@ph7>ph5, A1'@ph8>ph6.  All verified.
// Landing guarantees: vmcnt(6) at ph4/ph8 leaves exactly the 3 newest half-tiles
// in flight; everything older (= everything read in the next 4 phases) has landed.
// Prologue: T0 x4 + T1.{A0,B0,A1}, then vmcnt(6). Final iteration stages only
// T_last.B1 and drains with vmcnt(0) at ph4.

#define BAR   __builtin_amdgcn_s_barrier()
#define LGKM0 asm volatile("s_waitcnt lgkmcnt(0)" ::: "memory")
#define VM6   asm volatile("s_waitcnt vmcnt(6)" ::: "memory")
#define VM0   asm volatile("s_waitcnt vmcnt(0)" ::: "memory")

// AB: 0=A,1=B ; G: global base (already offset to block rows) ; H: half ; T: k-tile
#define STAGE(AB, G, H, T)                                                             \
  do {                                                                                 \
    _Pragma("unroll")                                                                  \
    for (int q = 0; q < 2; ++q) {                                                      \
      const int rl = wave * 16 + q * 8 + (lane >> 3);                                  \
      const int sc = (lane & 7) ^ (rl & 7);                                            \
      __builtin_amdgcn_global_load_lds(                                                \
          (gas_ptr)((G) + (size_t)((H) * 128 + rl) * K + (T) * 64 + sc * 8),           \
          (las_ptr)&sm[(T) & 1][AB][H][wave * 16 + q * 8][0], 16, 0, 0);               \
    }                                                                                  \
  } while (0)

#define LDA(DST, BUF, MH)                                                              \
  do {                                                                                 \
    _Pragma("unroll")                                                                  \
    for (int mi = 0; mi < 4; ++mi)                                                     \
      _Pragma("unroll")                                                                \
      for (int kc = 0; kc < 2; ++kc)                                                   \
        DST[mi][kc] = *(const bf16x8*)&sm[BUF][0][wm][(MH) * 64 + mi * 16 + col]       \
                                         [((kc * 4 + quad) ^ (col & 7)) << 3];         \
  } while (0)

#define LDB(BUF, NH)                                                                   \
  do {                                                                                 \
    _Pragma("unroll")                                                                  \
    for (int ni = 0; ni < 2; ++ni)                                                     \
      _Pragma("unroll")                                                                \
      for (int kc = 0; kc < 2; ++kc)                                                   \
        bb[ni][kc] = *(const bf16x8*)&sm[BUF][1][wn >> 1]                              \
                                        [(wn & 1) * 64 + (NH) * 32 + ni * 16 + col]    \
                                        [((kc * 4 + quad) ^ (col & 7)) << 3];          \
  } while (0)

#define MFMA16(MH, NH, AR)                                                             \
  do {                                                                                 \
    __builtin_amdgcn_s_setprio(1);                                                     \
    _Pragma("unroll")                                                                  \
    for (int mi = 0; mi < 4; ++mi)                                                     \
      _Pragma("unroll")                                                                \
      for (int ni = 0; ni < 2; ++ni)                                                   \
        _Pragma("unroll")                                                              \
        for (int kc = 0; kc < 2; ++kc)                                                 \
          acc[(MH) * 4 + mi][(NH) * 2 + ni] = __builtin_amdgcn_mfma_f32_16x16x32_bf16( \
              AR[mi][kc], bb[ni][kc], acc[(MH) * 4 + mi][(NH) * 2 + ni], 0, 0, 0);     \
    __builtin_amdgcn_s_setprio(0);                                                     \
  } while (0)

__global__ __launch_bounds__(512, 2) void gemm_bt_256(const u16* __restrict__ A,
                                                      const u16* __restrict__ B,
                                                      float* __restrict__ C,
                                                      int M, int N, int K) {
  __shared__ u16 sm[2][2][2][128][64];   // [buf][A/B][half][row][k] = 128 KiB
  const int tid  = threadIdx.x;
  const int wave = tid >> 6, lane = tid & 63;
  const int wm   = wave >> 2, wn = wave & 3;
  const int col  = lane & 15, quad = lane >> 4;

  // XCD-bijective block swizzle (valid when nwg % 8 == 0; grid here is 48x8=384)
  int bid = blockIdx.y * gridDim.x + blockIdx.x;
  const int nwg = gridDim.x * gridDim.y;
  if ((nwg & 7) == 0) bid = (bid & 7) * (nwg >> 3) + (bid >> 3);
  const int m0 = (bid / gridDim.x) * 256;
  const int n0 = (bid % gridDim.x) * 256;

  const u16* Ag = A + (size_t)m0 * K;
  const u16* Bg = B + (size_t)n0 * K;

  f32x4 acc[8][4] = {};
  bf16x8 a0[4][2], a1[4][2], bb[2][2];

  // prologue: T0 all 4 halves + T1.{A0,B0,A1} = 7 half-tiles (14 loads/lane)
  STAGE(0, Ag, 0, 0); STAGE(0, Ag, 1, 0);
  STAGE(1, Bg, 0, 0); STAGE(1, Bg, 1, 0);
  STAGE(0, Ag, 0, 1); STAGE(1, Bg, 0, 1); STAGE(0, Ag, 1, 1);
  VM6;   // T0 landed; T1.{A0,B0,A1} may stay in flight
  BAR;

  const int NIT = K >> 7;   // K / 128 (2 tiles per iteration)
  for (int i = 0; i < NIT - 1; ++i) {
    const int t0 = i * 2;
    // ---- ph1 (m0,n0) on buf0 / tile t0 | stage t'.B1 ----
    LDA(a0, 0, 0); LDB(0, 0); STAGE(1, Bg, 1, t0 + 1);
    BAR; LGKM0; MFMA16(0, 0, a0); BAR;
    // ---- ph2 (m1,n0) | stage (t+2).A0 ----
    LDA(a1, 0, 1); STAGE(0, Ag, 0, t0 + 2);
    BAR; LGKM0; MFMA16(1, 0, a1); BAR;
    // ---- ph3 (m1,n1) | stage (t+2).B0 ----
    LDB(0, 1); STAGE(1, Bg, 0, t0 + 2);
    BAR; LGKM0; MFMA16(1, 1, a1); BAR;
    // ---- ph4 (m0,n1): no ds_reads (a0,bb retained) | stage (t+2).A1 ; vmcnt(6) ----
    STAGE(0, Ag, 1, t0 + 2);
    BAR; LGKM0; MFMA16(0, 1, a0); VM6; BAR;
    // ---- ph5 (m0,n0) on buf1 / tile t0+1 | stage (t+2).B1 ----
    LDA(a0, 1, 0); LDB(1, 0); STAGE(1, Bg, 1, t0 + 2);
    BAR; LGKM0; MFMA16(0, 0, a0); BAR;
    // ---- ph6 (m1,n0) | stage (t+3).A0 ----
    LDA(a1, 1, 1); STAGE(0, Ag, 0, t0 + 3);
    BAR; LGKM0; MFMA16(1, 0, a1); BAR;
    // ---- ph7 (m1,n1) | stage (t+3).B0 ----
    LDB(1, 1); STAGE(1, Bg, 0, t0 + 3);
    BAR; LGKM0; MFMA16(1, 1, a1); BAR;
    // ---- ph8 (m0,n1) | stage (t+3).A1 ; vmcnt(6) ----
    STAGE(0, Ag, 1, t0 + 3);
    BAR; LGKM0; MFMA16(0, 1, a0); VM6; BAR;
  }
  // ---- final iteration: only T_last.B1 still needs staging; drain at ph4 --------
  {
    LDA(a0, 0, 0); LDB(0, 0); STAGE(1, Bg, 1, 2 * NIT - 1);
    BAR; LGKM0; MFMA16(0, 0, a0); BAR;
    LDA(a1, 0, 1);
    BAR; LGKM0; MFMA16(1, 0, a1); BAR;
    LDB(0, 1);
    BAR; LGKM0; MFMA16(1, 1, a1); BAR;
    BAR; LGKM0; MFMA16(0, 1, a0); VM0; BAR;
    LDA(a0, 1, 0); LDB(1, 0);
    BAR; LGKM0; MFMA16(0, 0, a0); BAR;
    LDA(a1, 1, 1);
    BAR; LGKM0; MFMA16(1, 0, a1); BAR;
    LDB(1, 1);
    BAR; LGKM0; MFMA16(1, 1, a1); BAR;
    LGKM0; MFMA16(0, 1, a0);
  }

  // ---- epilogue: fp32 C store --------------------------------------------------
#pragma unroll
  for (int mi = 0; mi < 8; ++mi)
#pragma unroll
    for (int ni = 0; ni < 4; ++ni)
#pragma unroll
      for (int r = 0; r < 4; ++r) {
        const int row = m0 + wm * 128 + mi * 16 + quad * 4 + r;
        const int cc  = n0 + wn * 64 + ni * 16 + col;
        C[(size_t)row * N + cc] = acc[mi][ni][r];
      }
}

#undef STAGE
#undef LDA
#undef LDB
#undef MFMA16
#undef BAR
#undef LGKM0
#undef VM6
#undef VM0

// ---------------- RoPE on Q (scale*log2e folded): QKV32 fp32 -> Qb bf16 -----------
__global__ __launch_bounds__(256) void rope_q_kernel(const float* __restrict__ qkv,
                                                     const float* __restrict__ rope,
                                                     u16* __restrict__ Qb) {
  const float qs = 0.08838834764831845f * 1.4426950408889634f;  // 1/sqrt(128) * log2(e)
  int idx = blockIdx.x * 256 + threadIdx.x;           // (bh, s, pair) : 64*1024*64
  int i = idx & 63, s = (idx >> 6) & 1023, bh = idx >> 16;
  int b = bh >> 5, h = bh & 31;
  const float* p = qkv + (size_t)(b * 1024 + s) * 12288 + h * 128 + 2 * i;
  float t0 = p[0], t1 = p[1];
  float c = rope[(s * 64 + i) * 2], sn = rope[(s * 64 + i) * 2 + 1];
  size_t o = ((size_t)bh * 1024 + s) * 128 + 2 * i;
  Qb[o]     = f2bf((t0 * c - t1 * sn) * qs);
  Qb[o + 1] = f2bf((t0 * sn + t1 * c) * qs);
}

// ---------------- RoPE on K: fp32 -> xk (d_out) AND Kb bf16, positions >= 1024 ----
__global__ __launch_bounds__(256) void rope_k_kernel(const float* __restrict__ qkv,
                                                     const float* __restrict__ rope,
                                                     float* __restrict__ xk,
                                                     u16* __restrict__ Kb) {
  int idx = blockIdx.x * 256 + threadIdx.x;
  int i = idx & 63, s = (idx >> 6) & 1023, bh = idx >> 16;
  int b = bh >> 5, h = bh & 31;
  const float* p = qkv + (size_t)(b * 1024 + s) * 12288 + 4096 + h * 128 + 2 * i;
  float t0 = p[0], t1 = p[1];
  float c = rope[(s * 64 + i) * 2], sn = rope[(s * 64 + i) * 2 + 1];
  float r0 = t0 * c - t1 * sn, r1 = t0 * sn + t1 * c;
  size_t o = ((size_t)bh * 2048 + 1024 + s) * 128 + 2 * i;
  xk[o] = r0; xk[o + 1] = r1;
  Kb[o] = f2bf(r0); Kb[o + 1] = f2bf(r1);
}

// ---------------- V new positions: fp32 -> xv (d_out), positions >= 1024 ----------
__global__ __launch_bounds__(256) void copy_v_kernel(const float* __restrict__ qkv,
                                                     float* __restrict__ xv) {
  int idx = blockIdx.x * 256 + threadIdx.x;           // (bh, s, d) : 64*1024*128
  int d = idx & 127, s = (idx >> 7) & 1023, bh = idx >> 17;
  int b = bh >> 5, h = bh & 31;
  xv[((size_t)bh * 2048 + 1024 + s) * 128 + d] =
      qkv[(size_t)(b * 1024 + s) * 12288 + 8192 + h * 128 + d];
}

// ---------------- K cache: fp32 -> xk fp32 + Kb bf16 at t < 1024 ------------------
__global__ __launch_bounds__(256) void cache_copy_k_kernel(const float* __restrict__ src,
                                                           float* __restrict__ dst,
                                                           u16* __restrict__ dstb) {
  int idx = blockIdx.x * 256 + threadIdx.x;           // 64*1024*128
  int d = idx & 127, t = (idx >> 7) & 1023, bh = idx >> 17;
  float v = src[idx];
  size_t o = ((size_t)bh * 2048 + t) * 128 + d;
  dst[o] = v;
  dstb[o] = f2bf(v);
}

// ---------------- V cache: fp32 -> xv fp32 at t < 1024 ----------------------------
__global__ __launch_bounds__(256) void cache_copy_v_kernel(const float* __restrict__ src,
                                                           float* __restrict__ dst) {
  int idx = blockIdx.x * 256 + threadIdx.x;
  int d = idx & 127, t = (idx >> 7) & 1023, bh = idx >> 17;
  dst[((size_t)bh * 2048 + t) * 128 + d] = src[idx];
}

// ---------------- transpose: xv fp32 (bh, 2048 t, 128 d) -> VT bf16 (bh, 128 d, 2048 t)
__global__ __launch_bounds__(256) void transpose_v_kernel(const float* __restrict__ src,
                                                          u16* __restrict__ dst) {
  __shared__ float tile[32][33];
  int bh = blockIdx.z;
  int t0 = blockIdx.x * 32, d0 = blockIdx.y * 32;
  int tx = threadIdx.x & 31, ty = threadIdx.x >> 5;
  const float* s = src + ((size_t)bh * 2048 + t0) * 128 + d0;
#pragma unroll
  for (int i = 0; i < 4; ++i)
    tile[ty + i * 8][tx] = s[(ty + i * 8) * 128 + tx];
  __syncthreads();
  u16* dp = dst + ((size_t)bh * 128 + d0) * 2048 + t0;
#pragma unroll
  for (int i = 0; i < 4; ++i)
    dp[(ty + i * 8) * 2048 + tx] = f2bf(tile[tx][ty + i * 8]);
}

// ---------------- flash attention v2: 1 block = (bh, 128 q rows), LDS K/V staging --
// wave handles 32 q rows (2 m-tiles of 16); t-step = 64; K/V XOR-swizzled in LDS.
__global__ __launch_bounds__(256, 2) void attn_kernel(const u16* __restrict__ Qb,
                                                      const u16* __restrict__ Kb,
                                                      const u16* __restrict__ VT,
                                                      u16* __restrict__ ctx) {
  const int bh = blockIdx.y;
  const int b = bh >> 5, h = bh & 31;
  const int wave = threadIdx.x >> 6, lane = threadIdx.x & 63;
  const int col = lane & 15, quad = lane >> 4;
  const int qblk = blockIdx.x * 128;
  const int qw = qblk + wave * 32;          // this wave's 32 q rows

  __shared__ u16 Ks[64][128];   // (t, d), chunk-XOR-swizzled: 16 KB
  __shared__ u16 Vs[128][64];   // (d, t), chunk-XOR-swizzled: 16 KB
  __shared__ u16 Plds[4][32][64];  // per-wave P, chunk-XOR-swizzled: 16 KB

  const u16* Qh = Qb + (size_t)bh * 1024 * 128;
  const u16* Kh = Kb + (size_t)bh * 2048 * 128;
  const u16* Vh = VT + (size_t)bh * 128 * 2048;

  // Q fragments: A-operand layout (m = col, k = quad*8 + j within kc*32)
  bf16x8 qf[2][4];
#pragma unroll
  for (int mt = 0; mt < 2; ++mt)
#pragma unroll
    for (int kc = 0; kc < 4; ++kc)
      qf[mt][kc] = *(const bf16x8*)&Qh[(size_t)(qw + mt * 16 + col) * 128 + kc * 32 + quad * 8];

  f32x4 o[2][8] = {};
  float m_r[2][4], l_r[2][4];
#pragma unroll
  for (int mt = 0; mt < 2; ++mt)
#pragma unroll
    for (int r = 0; r < 4; ++r) { m_r[mt][r] = -1e30f; l_r[mt][r] = 0.0f; }

  const int t_end = 1024 + qblk + 128;

  for (int t0 = 0; t0 < t_end; t0 += 64) {
    // ---- stage K tile (64 t x 128 d): 4 issues x 4 waves x (4 rows, 16 chunks) ----
#pragma unroll
    for (int j = 0; j < 4; ++j) {
      const int g = j * 4 + wave;
      const int r = g * 4 + (lane >> 4);              // t row 0..63
      const int cg = (lane & 15) ^ (r & 15);          // source chunk (16B) for XOR swizzle
      __builtin_amdgcn_global_load_lds((gas_ptr)(Kh + (size_t)(t0 + r) * 128 + cg * 8),
                                       (las_ptr)&Ks[g * 4][0], 16, 0, 0);
    }
    // ---- stage V^T tile (128 d x 64 t): 4 issues x 4 waves x (8 rows, 8 chunks) ---
#pragma unroll
    for (int j = 0; j < 4; ++j) {
      const int g = j * 4 + wave;
      const int r = g * 8 + (lane >> 3);              // d row 0..127
      const int cg = (lane & 7) ^ (r & 7);
      __builtin_amdgcn_global_load_lds((gas_ptr)(Vh + (size_t)r * 2048 + t0 + cg * 8),
                                       (las_ptr)&Vs[g * 8][0], 16, 0, 0);
    }
    __syncthreads();

    // ---- QK^T: S[2 mt][4 tt] over K=128 -----------------------------------------
    f32x4 s[2][4];
#pragma unroll
    for (int mt = 0; mt < 2; ++mt)
#pragma unroll
      for (int tt = 0; tt < 4; ++tt) s[mt][tt] = (f32x4){0.f, 0.f, 0.f, 0.f};
#pragma unroll
    for (int kc = 0; kc < 4; ++kc) {
      bf16x8 kf[4];
#pragma unroll
      for (int tt = 0; tt < 4; ++tt)
        kf[tt] = *(const bf16x8*)&Ks[tt * 16 + col][(((kc * 4 + quad) ^ col) & 15) * 8];
#pragma unroll
      for (int mt = 0; mt < 2; ++mt)
#pragma unroll
        for (int tt = 0; tt < 4; ++tt)
          s[mt][tt] = __builtin_amdgcn_mfma_f32_16x16x32_bf16(qf[mt][kc], kf[tt], s[mt][tt], 0, 0, 0);
    }

    // ---- online softmax (scores already in log2 domain, scale folded into Q) -----
#pragma unroll
    for (int mt = 0; mt < 2; ++mt)
#pragma unroll
      for (int r = 0; r < 4; ++r) {
        const int qabs = 1024 + qw + mt * 16 + quad * 4 + r;
        float v[4];
#pragma unroll
        for (int tt = 0; tt < 4; ++tt) {
          v[tt] = s[mt][tt][r];
          if (t0 + tt * 16 + col > qabs) v[tt] = -1e30f;
        }
        float mx = fmaxf(fmaxf(v[0], v[1]), fmaxf(v[2], v[3]));
        mx = fmaxf(mx, __shfl_xor(mx, 1));
        mx = fmaxf(mx, __shfl_xor(mx, 2));
        mx = fmaxf(mx, __shfl_xor(mx, 4));
        mx = fmaxf(mx, __shfl_xor(mx, 8));
        const float mnew  = fmaxf(m_r[mt][r], mx);
        const float alpha = fast_exp2(m_r[mt][r] - mnew);
        m_r[mt][r] = mnew;
        float sum = 0.f;
#pragma unroll
        for (int tt = 0; tt < 4; ++tt) {
          v[tt] = fast_exp2(v[tt] - mnew);
          sum += v[tt];
        }
        sum += __shfl_xor(sum, 1);
        sum += __shfl_xor(sum, 2);
        sum += __shfl_xor(sum, 4);
        sum += __shfl_xor(sum, 8);
        l_r[mt][r] = l_r[mt][r] * alpha + sum;
#pragma unroll
        for (int dt = 0; dt < 8; ++dt) o[mt][dt][r] *= alpha;
        // write P (C-layout -> chunk-swizzled LDS for A-operand reads)
        const int prow = mt * 16 + quad * 4 + r;
#pragma unroll
        for (int tt = 0; tt < 4; ++tt) {
          const int t = tt * 16 + col;
          const int c = (t >> 3) ^ (prow & 7);
          Plds[wave][prow][c * 8 + (t & 7)] = f2bf(v[tt]);
        }
      }
    asm volatile("s_waitcnt lgkmcnt(0)" ::: "memory");

    // ---- P fragments + PV --------------------------------------------------------
    bf16x8 pf[2][2];
#pragma unroll
    for (int mt = 0; mt < 2; ++mt)
#pragma unroll
      for (int kk = 0; kk < 2; ++kk)
        pf[mt][kk] = *(const bf16x8*)&Plds[wave][mt * 16 + col][(((kk * 4 + quad) ^ (col & 7))) * 8];
#pragma unroll
    for (int kk = 0; kk < 2; ++kk)
#pragma unroll
      for (int dt = 0; dt < 8; ++dt) {
        bf16x8 vf = *(const bf16x8*)&Vs[dt * 16 + col][(((kk * 4 + quad) ^ (col & 7))) * 8];
#pragma unroll
        for (int mt = 0; mt < 2; ++mt)
          o[mt][dt] = __builtin_amdgcn_mfma_f32_16x16x32_bf16(pf[mt][kk], vf, o[mt][dt], 0, 0, 0);
      }
    __syncthreads();   // Ks/Vs fully consumed before next staging
  }

  // ---- epilogue: normalize + store ctx bf16 (b, s, h, d) --------------------------
  float inv[2][4];
#pragma unroll
  for (int mt = 0; mt < 2; ++mt)
#pragma unroll
    for (int r = 0; r < 4; ++r) inv[mt][r] = 1.0f / l_r[mt][r];
#pragma unroll
  for (int mt = 0; mt < 2; ++mt)
#pragma unroll
    for (int dt = 0; dt < 8; ++dt)
#pragma unroll
      for (int r = 0; r < 4; ++r) {
        const int q = qw + mt * 16 + quad * 4 + r;
        const int d = dt * 16 + col;
        ctx[(size_t)(b * 1024 + q) * 4096 + h * 128 + d] = f2bf(o[mt][dt][r] * inv[mt][r]);
      }
}

// ----------------------------------------------------------------------------------
extern "C" void kernel_launch(void* const* d_in, const int* in_sizes, int n_in,
                              void* d_out, int out_size, void* d_ws, size_t ws_size,
                              hipStream_t stream) {
  const float* x    = (const float*)d_in[0];
  const float* kc   = (const float*)d_in[1];
  const float* vc   = (const float*)d_in[2];
  const float* rope = (const float*)d_in[3];
  const float* Wq   = (const float*)d_in[4];
  const float* Wk   = (const float*)d_in[5];
  const float* Wv   = (const float*)d_in[6];
  const float* Wo   = (const float*)d_in[7];

  float* out = (float*)d_out;                 // (2,1024,4096)
  float* xk  = out + 8388608;                 // (2,32,2048,128)
  float* xv  = out + 25165824;                // (2,32,2048,128)

  char* ws = (char*)d_ws;
  u16*   Xb   = (u16*)(ws + 0);               // x bf16          16,777,216 B
  u16*   Wc   = (u16*)(ws + 16777216);        // Wqkv bf16      100,663,296 B
  u16*   KbB  = (u16*)(ws + 16777216);        //   after GEMM1: K bf16 (b,h,2048,128)
  u16*   VTb  = (u16*)(ws + 50331648);        //   after GEMM1: V^T bf16 (b,h,128,2048)
  float* QKV  = (float*)(ws + 117440512);     // QKV fp32 (2048 x 12288)
  u16*   Wob  = (u16*)(ws + 117440512);       //   after rope: Wo bf16
  u16*   ctxb = (u16*)(ws + 150994944);       //   after rope: ctx bf16
  u16*   Qbb  = (u16*)(ws + 218103808);       // Q bf16 (b,h,1024,128), scale folded

  cvt_f32_bf16<<<8192, 256, 0, stream>>>(x, Xb, 8388608);
  cvt_f32_bf16<<<16384, 256, 0, stream>>>(Wq, Wc, 16777216);
  cvt_f32_bf16<<<16384, 256, 0, stream>>>(Wk, Wc + 16777216, 16777216);
  cvt_f32_bf16<<<16384, 256, 0, stream>>>(Wv, Wc + 33554432, 16777216);
  gemm_bt_256<<<dim3(48, 8), 512, 0, stream>>>(Xb, Wc, QKV, 2048, 12288, 4096);
  rope_q_kernel<<<16384, 256, 0, stream>>>(QKV, rope, Qbb);
  rope_k_kernel<<<16384, 256, 0, stream>>>(QKV, rope, xk, KbB);
  copy_v_kernel<<<32768, 256, 0, stream>>>(QKV, xv);
  cache_copy_k_kernel<<<32768, 256, 0, stream>>>(kc, xk, KbB);
  cache_copy_v_kernel<<<32768, 256, 0, stream>>>(vc, xv);
  transpose_v_kernel<<<dim3(64, 4, 64), 256, 0, stream>>>(xv, VTb);
  cvt_f32_bf16<<<16384, 256, 0, stream>>>(Wo, Wob, 16777216);
  attn_kernel<<<dim3(8, 64), 256, 0, stream>>>(Qbb, KbB, VTb, ctxb);
  gemm_bt<<<dim3(32, 16), 256, 0, stream>>>(ctxb, Wob, out, 2048, 4096, 4096);
}

// Round 5
// 1003.192 us; speedup vs baseline: 1.0136x; 1.0136x over previous
//
#include <hip/hip_runtime.h>
#include <cstdint>
#include <cstddef>

typedef unsigned short u16;
typedef __attribute__((ext_vector_type(8))) short bf16x8;   // 8 bf16 = 4 VGPRs
typedef __attribute__((ext_vector_type(4))) float f32x4;    // MFMA 16x16 C/D

using gas_ptr = const __attribute__((address_space(1))) void*;
using las_ptr = __attribute__((address_space(3))) void*;

__device__ __forceinline__ u16 f2bf(float f) {
  union { float f; unsigned int u; } v; v.f = f;
  unsigned int u = v.u;
  return (u16)((u + 0x7fffu + ((u >> 16) & 1u)) >> 16);  // RNE
}

__device__ __forceinline__ float fast_exp2(float x) {
  return __builtin_amdgcn_exp2f(x);   // raw v_exp_f32
}

// ---------------- elementwise fp32 -> bf16 convert (vectorized x4) ----------------
__global__ __launch_bounds__(256) void cvt_f32_bf16(const float* __restrict__ src,
                                                    u16* __restrict__ dst, int n) {
  int i = (blockIdx.x * 256 + threadIdx.x) * 4;
  if (i >= n) return;
  float4 v = *(const float4*)(src + i);
  ushort4 o;
  o.x = f2bf(v.x); o.y = f2bf(v.y); o.z = f2bf(v.z); o.w = f2bf(v.w);
  *(ushort4*)(dst + i) = o;
}

// ---------------- m97-style bf16 GEMM: C[M,N] = A[M,K] * B[N,K]^T (fp32 out) ------
// kept for the Wo GEMM (grid 32x16 = 512 blocks; a 256^2 tile would leave half the
// CUs idle at M=2048,N=4096).
__global__ __launch_bounds__(256) void gemm_bt(const u16* __restrict__ A,
                                               const u16* __restrict__ B,
                                               float* __restrict__ C,
                                               int M, int N, int K) {
  __shared__ u16 As[128][32];
  __shared__ u16 Bs[128][32];
  const int m0 = blockIdx.y * 128, n0 = blockIdx.x * 128;
  const int tid = threadIdx.x;
  const int wave = tid >> 6, lane = tid & 63;
  const int wm = (wave & 1) * 64, wn = (wave >> 1) * 64;
  const int srow = lane >> 2, skoff = (lane & 3) * 8;
  const int col = lane & 15, quad = lane >> 4;
  f32x4 acc[4][4] = {};
  for (int k0 = 0; k0 < K; k0 += 32) {
#pragma unroll
    for (int r = 0; r < 2; ++r) {
      const u16* ga = A + (size_t)(m0 + r * 64 + wave * 16 + srow) * K + k0 + skoff;
      const u16* gb = B + (size_t)(n0 + r * 64 + wave * 16 + srow) * K + k0 + skoff;
      __builtin_amdgcn_global_load_lds((gas_ptr)ga, (las_ptr)&As[r * 64 + wave * 16][0], 16, 0, 0);
      __builtin_amdgcn_global_load_lds((gas_ptr)gb, (las_ptr)&Bs[r * 64 + wave * 16][0], 16, 0, 0);
    }
    __syncthreads();
    bf16x8 af[4], bfr[4];
#pragma unroll
    for (int t = 0; t < 4; ++t) {
      af[t]  = *(const bf16x8*)&As[wm + t * 16 + col][quad * 8];
      bfr[t] = *(const bf16x8*)&Bs[wn + t * 16 + col][quad * 8];
    }
#pragma unroll
    for (int mt = 0; mt < 4; ++mt)
#pragma unroll
      for (int nt = 0; nt < 4; ++nt)
        acc[mt][nt] = __builtin_amdgcn_mfma_f32_16x16x32_bf16(af[mt], bfr[nt], acc[mt][nt], 0, 0, 0);
    __syncthreads();
  }
#pragma unroll
  for (int mt = 0; mt < 4; ++mt)
#pragma unroll
    for (int nt = 0; nt < 4; ++nt)
#pragma unroll
      for (int r = 0; r < 4; ++r) {
        const int row  = m0 + wm + mt * 16 + quad * 4 + r;
        const int ccol = n0 + wn + nt * 16 + col;
        C[(size_t)row * N + ccol] = acc[mt][nt][r];
      }
}

// ---------------- 256x256 8-phase bf16 GEMM (T2+T3+T4+T5), C = A[M,K] * B[N,K]^T --
// Round-2 findings: vmcnt depth is NOT the limiter (vmcnt(6) regressed). The limiter
// is staging BANDWIDTH: the old 1D XCD chunking gave each XCD a full m-row (48
// blocks, 48 distinct B panels) -> B working set 64 MB vs 4 MB L2 -> each XCD
// streamed ~96 MB of B from L3/HBM (FETCH_SIZE 420 MB vs 117 ideal).
// Fix: 2D XCD chunk. Hardware round-robins bid%8 across XCDs, so XCD x = bid&7,
// per-XCD rank r = bid>>3. Chunk = 8m x 6n, column-major within chunk:
//   m = r & 7 ; n = x*6 + (r>>3).
// The 32 initially-resident blocks/XCD form an 8m x 4n pane: each B panel shared by
// 8 lockstep blocks, each A panel by 4 -> concurrent L2 reuse; B fetched once
// chip-wide (n-columns partitioned by XCD).
// Schedule = round-1 stream (measured best): vmcnt(4), 2 half-tiles ahead.

#define BAR   __builtin_amdgcn_s_barrier()
#define LGKM0 asm volatile("s_waitcnt lgkmcnt(0)" ::: "memory")
#define VM4   asm volatile("s_waitcnt vmcnt(4)" ::: "memory")
#define VM0   asm volatile("s_waitcnt vmcnt(0)" ::: "memory")

// AB: 0=A,1=B ; G: global base (already offset to block rows) ; H: half ; T: k-tile
#define STAGE(AB, G, H, T)                                                             \
  do {                                                                                 \
    _Pragma("unroll")                                                                  \
    for (int q = 0; q < 2; ++q) {                                                      \
      const int rl = wave * 16 + q * 8 + (lane >> 3);                                  \
      const int sc = (lane & 7) ^ (rl & 7);                                            \
      __builtin_amdgcn_global_load_lds(                                                \
          (gas_ptr)((G) + (size_t)((H) * 128 + rl) * K + (T) * 64 + sc * 8),           \
          (las_ptr)&sm[(T) & 1][AB][H][wave * 16 + q * 8][0], 16, 0, 0);               \
    }                                                                                  \
  } while (0)

#define LDA(DST, BUF, MH)                                                              \
  do {                                                                                 \
    _Pragma("unroll")                                                                  \
    for (int mi = 0; mi < 4; ++mi)                                                     \
      _Pragma("unroll")                                                                \
      for (int kc = 0; kc < 2; ++kc)                                                   \
        DST[mi][kc] = *(const bf16x8*)&sm[BUF][0][wm][(MH) * 64 + mi * 16 + col]       \
                                         [((kc * 4 + quad) ^ (col & 7)) << 3];         \
  } while (0)

#define LDB(BUF, NH)                                                                   \
  do {                                                                                 \
    _Pragma("unroll")                                                                  \
    for (int ni = 0; ni < 2; ++ni)                                                     \
      _Pragma("unroll")                                                                \
      for (int kc = 0; kc < 2; ++kc)                                                   \
        bb[ni][kc] = *(const bf16x8*)&sm[BUF][1][wn >> 1]                              \
                                        [(wn & 1) * 64 + (NH) * 32 + ni * 16 + col]    \
                                        [((kc * 4 + quad) ^ (col & 7)) << 3];          \
  } while (0)

#define MFMA16(MH, NH, AR)                                                             \
  do {                                                                                 \
    __builtin_amdgcn_s_setprio(1);                                                     \
    _Pragma("unroll")                                                                  \
    for (int mi = 0; mi < 4; ++mi)                                                     \
      _Pragma("unroll")                                                                \
      for (int ni = 0; ni < 2; ++ni)                                                   \
        _Pragma("unroll")                                                              \
        for (int kc = 0; kc < 2; ++kc)                                                 \
          acc[(MH) * 4 + mi][(NH) * 2 + ni] = __builtin_amdgcn_mfma_f32_16x16x32_bf16( \
              AR[mi][kc], bb[ni][kc], acc[(MH) * 4 + mi][(NH) * 2 + ni], 0, 0, 0);     \
    __builtin_amdgcn_s_setprio(0);                                                     \
  } while (0)

__global__ __launch_bounds__(512, 2) void gemm_bt_256(const u16* __restrict__ A,
                                                      const u16* __restrict__ B,
                                                      float* __restrict__ C,
                                                      int M, int N, int K) {
  __shared__ u16 sm[2][2][2][128][64];   // [buf][A/B][half][row][k] = 128 KiB
  const int tid  = threadIdx.x;
  const int wave = tid >> 6, lane = tid & 63;
  const int wm   = wave >> 2, wn = wave & 3;
  const int col  = lane & 15, quad = lane >> 4;

  // ---- 2D XCD-chunked block mapping (see header comment) ----
  const int bid = blockIdx.y * gridDim.x + blockIdx.x;
  int m_idx, n_idx;
  if (gridDim.x == 48 && gridDim.y == 8) {
    const int x = bid & 7;          // XCD (hardware round-robin on dispatch index)
    const int r = bid >> 3;         // rank within XCD, 0..47
    m_idx = r & 7;                  // column-major within the 8m x 6n chunk
    n_idx = x * 6 + (r >> 3);
  } else {
    m_idx = bid / gridDim.x;
    n_idx = bid % gridDim.x;
  }
  const int m0 = m_idx * 256;
  const int n0 = n_idx * 256;

  const u16* Ag = A + (size_t)m0 * K;
  const u16* Bg = B + (size_t)n0 * K;

  f32x4 acc[8][4] = {};
  bf16x8 a0[4][2], a1[4][2], bb[2][2];

  // prologue: tile0 (A0,A1,B0,B1 -> buf0) + tile1 A halves (-> buf1) = 12 loads/lane
  STAGE(0, Ag, 0, 0); STAGE(0, Ag, 1, 0);
  STAGE(1, Bg, 0, 0); STAGE(1, Bg, 1, 0);
  STAGE(0, Ag, 0, 1); STAGE(0, Ag, 1, 1);
  VM4;   // tile0 landed; tile1 A halves may stay in flight
  BAR;

  const int NIT = K >> 7;   // K / 128 (2 tiles per iteration)
  for (int i = 0; i < NIT - 1; ++i) {
    const int t0 = i * 2;
    // ---- ph1 (m0,n0) on buf0 / tile t0 ----
    LDA(a0, 0, 0); LDB(0, 0); STAGE(1, Bg, 0, t0 + 1);
    BAR; LGKM0; MFMA16(0, 0, a0); BAR;
    // ---- ph2 (m1,n0) ----
    LDA(a1, 0, 1); STAGE(1, Bg, 1, t0 + 1);
    BAR; LGKM0; MFMA16(1, 0, a1); BAR;
    // ---- ph3 (m1,n1) ----
    LDB(0, 1); STAGE(0, Ag, 0, t0 + 2);
    BAR; LGKM0; MFMA16(1, 1, a1); BAR;
    // ---- ph4 (m0,n1): no ds_reads (a0,bb retained) ----
    STAGE(0, Ag, 1, t0 + 2);
    BAR; LGKM0; MFMA16(0, 1, a0); VM4; BAR;
    // ---- ph5 (m0,n0) on buf1 / tile t0+1 ----
    LDA(a0, 1, 0); LDB(1, 0); STAGE(1, Bg, 0, t0 + 2);
    BAR; LGKM0; MFMA16(0, 0, a0); BAR;
    // ---- ph6 (m1,n0) ----
    LDA(a1, 1, 1); STAGE(1, Bg, 1, t0 + 2);
    BAR; LGKM0; MFMA16(1, 0, a1); BAR;
    // ---- ph7 (m1,n1) ----
    LDB(1, 1); STAGE(0, Ag, 0, t0 + 3);
    BAR; LGKM0; MFMA16(1, 1, a1); BAR;
    // ---- ph8 (m0,n1) ----
    STAGE(0, Ag, 1, t0 + 3);
    BAR; LGKM0; MFMA16(0, 1, a0); VM4; BAR;
  }
  // ---- last iteration: only the final tile's B halves still need staging --------
  {
    const int t0 = 2 * NIT - 2;
    LDA(a0, 0, 0); LDB(0, 0); STAGE(1, Bg, 0, t0 + 1);
    BAR; LGKM0; MFMA16(0, 0, a0); BAR;
    LDA(a1, 0, 1); STAGE(1, Bg, 1, t0 + 1);
    BAR; LGKM0; MFMA16(1, 0, a1); BAR;
    LDB(0, 1);
    BAR; LGKM0; MFMA16(1, 1, a1); BAR;
    BAR; LGKM0; MFMA16(0, 1, a0); VM0; BAR;
    LDA(a0, 1, 0); LDB(1, 0);
    BAR; LGKM0; MFMA16(0, 0, a0); BAR;
    LDA(a1, 1, 1);
    BAR; LGKM0; MFMA16(1, 0, a1); BAR;
    LDB(1, 1);
    BAR; LGKM0; MFMA16(1, 1, a1); BAR;
    LGKM0; MFMA16(0, 1, a0);
  }

  // ---- epilogue: fp32 C store --------------------------------------------------
#pragma unroll
  for (int mi = 0; mi < 8; ++mi)
#pragma unroll
    for (int ni = 0; ni < 4; ++ni)
#pragma unroll
      for (int r = 0; r < 4; ++r) {
        const int row = m0 + wm * 128 + mi * 16 + quad * 4 + r;
        const int cc  = n0 + wn * 64 + ni * 16 + col;
        C[(size_t)row * N + cc] = acc[mi][ni][r];
      }
}

#undef STAGE
#undef LDA
#undef LDB
#undef MFMA16
#undef BAR
#undef LGKM0
#undef VM4
#undef VM0

// ---------------- RoPE on Q (scale*log2e folded): QKV32 fp32 -> Qb bf16 -----------
__global__ __launch_bounds__(256) void rope_q_kernel(const float* __restrict__ qkv,
                                                     const float* __restrict__ rope,
                                                     u16* __restrict__ Qb) {
  const float qs = 0.08838834764831845f * 1.4426950408889634f;  // 1/sqrt(128) * log2(e)
  int idx = blockIdx.x * 256 + threadIdx.x;           // (bh, s, pair) : 64*1024*64
  int i = idx & 63, s = (idx >> 6) & 1023, bh = idx >> 16;
  int b = bh >> 5, h = bh & 31;
  const float* p = qkv + (size_t)(b * 1024 + s) * 12288 + h * 128 + 2 * i;
  float t0 = p[0], t1 = p[1];
  float c = rope[(s * 64 + i) * 2], sn = rope[(s * 64 + i) * 2 + 1];
  size_t o = ((size_t)bh * 1024 + s) * 128 + 2 * i;
  Qb[o]     = f2bf((t0 * c - t1 * sn) * qs);
  Qb[o + 1] = f2bf((t0 * sn + t1 * c) * qs);
}

// ---------------- RoPE on K: fp32 -> xk (d_out) AND Kb bf16, positions >= 1024 ----
__global__ __launch_bounds__(256) void rope_k_kernel(const float* __restrict__ qkv,
                                                     const float* __restrict__ rope,
                                                     float* __restrict__ xk,
                                                     u16* __restrict__ Kb) {
  int idx = blockIdx.x * 256 + threadIdx.x;
  int i = idx & 63, s = (idx >> 6) & 1023, bh = idx >> 16;
  int b = bh >> 5, h = bh & 31;
  const float* p = qkv + (size_t)(b * 1024 + s) * 12288 + 4096 + h * 128 + 2 * i;
  float t0 = p[0], t1 = p[1];
  float c = rope[(s * 64 + i) * 2], sn = rope[(s * 64 + i) * 2 + 1];
  float r0 = t0 * c - t1 * sn, r1 = t0 * sn + t1 * c;
  size_t o = ((size_t)bh * 2048 + 1024 + s) * 128 + 2 * i;
  xk[o] = r0; xk[o + 1] = r1;
  Kb[o] = f2bf(r0); Kb[o + 1] = f2bf(r1);
}

// ---------------- V new positions: fp32 -> xv (d_out), positions >= 1024 ----------
__global__ __launch_bounds__(256) void copy_v_kernel(const float* __restrict__ qkv,
                                                     float* __restrict__ xv) {
  int idx = blockIdx.x * 256 + threadIdx.x;           // (bh, s, d) : 64*1024*128
  int d = idx & 127, s = (idx >> 7) & 1023, bh = idx >> 17;
  int b = bh >> 5, h = bh & 31;
  xv[((size_t)bh * 2048 + 1024 + s) * 128 + d] =
      qkv[(size_t)(b * 1024 + s) * 12288 + 8192 + h * 128 + d];
}

// ---------------- K cache: fp32 -> xk fp32 + Kb bf16 at t < 1024 ------------------
__global__ __launch_bounds__(256) void cache_copy_k_kernel(const float* __restrict__ src,
                                                           float* __restrict__ dst,
                                                           u16* __restrict__ dstb) {
  int idx = blockIdx.x * 256 + threadIdx.x;           // 64*1024*128
  int d = idx & 127, t = (idx >> 7) & 1023, bh = idx >> 17;
  float v = src[idx];
  size_t o = ((size_t)bh * 2048 + t) * 128 + d;
  dst[o] = v;
  dstb[o] = f2bf(v);
}

// ---------------- V cache: fp32 -> xv fp32 at t < 1024 ----------------------------
__global__ __launch_bounds__(256) void cache_copy_v_kernel(const float* __restrict__ src,
                                                           float* __restrict__ dst) {
  int idx = blockIdx.x * 256 + threadIdx.x;
  int d = idx & 127, t = (idx >> 7) & 1023, bh = idx >> 17;
  dst[((size_t)bh * 2048 + t) * 128 + d] = src[idx];
}

// ---------------- transpose: xv fp32 (bh, 2048 t, 128 d) -> VT bf16 (bh, 128 d, 2048 t)
__global__ __launch_bounds__(256) void transpose_v_kernel(const float* __restrict__ src,
                                                          u16* __restrict__ dst) {
  __shared__ float tile[32][33];
  int bh = blockIdx.z;
  int t0 = blockIdx.x * 32, d0 = blockIdx.y * 32;
  int tx = threadIdx.x & 31, ty = threadIdx.x >> 5;
  const float* s = src + ((size_t)bh * 2048 + t0) * 128 + d0;
#pragma unroll
  for (int i = 0; i < 4; ++i)
    tile[ty + i * 8][tx] = s[(ty + i * 8) * 128 + tx];
  __syncthreads();
  u16* dp = dst + ((size_t)bh * 128 + d0) * 2048 + t0;
#pragma unroll
  for (int i = 0; i < 4; ++i)
    dp[(ty + i * 8) * 2048 + tx] = f2bf(tile[tx][ty + i * 8]);
}

// ---------------- flash attention v2: 1 block = (bh, 128 q rows), LDS K/V staging --
// wave handles 32 q rows (2 m-tiles of 16); t-step = 64; K/V XOR-swizzled in LDS.
__global__ __launch_bounds__(256, 2) void attn_kernel(const u16* __restrict__ Qb,
                                                      const u16* __restrict__ Kb,
                                                      const u16* __restrict__ VT,
                                                      u16* __restrict__ ctx) {
  const int bh = blockIdx.y;
  const int b = bh >> 5, h = bh & 31;
  const int wave = threadIdx.x >> 6, lane = threadIdx.x & 63;
  const int col = lane & 15, quad = lane >> 4;
  const int qblk = blockIdx.x * 128;
  const int qw = qblk + wave * 32;          // this wave's 32 q rows

  __shared__ u16 Ks[64][128];   // (t, d), chunk-XOR-swizzled: 16 KB
  __shared__ u16 Vs[128][64];   // (d, t), chunk-XOR-swizzled: 16 KB
  __shared__ u16 Plds[4][32][64];  // per-wave P, chunk-XOR-swizzled: 16 KB

  const u16* Qh = Qb + (size_t)bh * 1024 * 128;
  const u16* Kh = Kb + (size_t)bh * 2048 * 128;
  const u16* Vh = VT + (size_t)bh * 128 * 2048;

  // Q fragments: A-operand layout (m = col, k = quad*8 + j within kc*32)
  bf16x8 qf[2][4];
#pragma unroll
  for (int mt = 0; mt < 2; ++mt)
#pragma unroll
    for (int kc = 0; kc < 4; ++kc)
      qf[mt][kc] = *(const bf16x8*)&Qh[(size_t)(qw + mt * 16 + col) * 128 + kc * 32 + quad * 8];

  f32x4 o[2][8] = {};
  float m_r[2][4], l_r[2][4];
#pragma unroll
  for (int mt = 0; mt < 2; ++mt)
#pragma unroll
    for (int r = 0; r < 4; ++r) { m_r[mt][r] = -1e30f; l_r[mt][r] = 0.0f; }

  const int t_end = 1024 + qblk + 128;

  for (int t0 = 0; t0 < t_end; t0 += 64) {
    // ---- stage K tile (64 t x 128 d): 4 issues x 4 waves x (4 rows, 16 chunks) ----
#pragma unroll
    for (int j = 0; j < 4; ++j) {
      const int g = j * 4 + wave;
      const int r = g * 4 + (lane >> 4);              // t row 0..63
      const int cg = (lane & 15) ^ (r & 15);          // source chunk (16B) for XOR swizzle
      __builtin_amdgcn_global_load_lds((gas_ptr)(Kh + (size_t)(t0 + r) * 128 + cg * 8),
                                       (las_ptr)&Ks[g * 4][0], 16, 0, 0);
    }
    // ---- stage V^T tile (128 d x 64 t): 4 issues x 4 waves x (8 rows, 8 chunks) ---
#pragma unroll
    for (int j = 0; j < 4; ++j) {
      const int g = j * 4 + wave;
      const int r = g * 8 + (lane >> 3);              // d row 0..127
      const int cg = (lane & 7) ^ (r & 7);
      __builtin_amdgcn_global_load_lds((gas_ptr)(Vh + (size_t)r * 2048 + t0 + cg * 8),
                                       (las_ptr)&Vs[g * 8][0], 16, 0, 0);
    }
    __syncthreads();

    // ---- QK^T: S[2 mt][4 tt] over K=128 -----------------------------------------
    f32x4 s[2][4];
#pragma unroll
    for (int mt = 0; mt < 2; ++mt)
#pragma unroll
      for (int tt = 0; tt < 4; ++tt) s[mt][tt] = (f32x4){0.f, 0.f, 0.f, 0.f};
#pragma unroll
    for (int kc = 0; kc < 4; ++kc) {
      bf16x8 kf[4];
#pragma unroll
      for (int tt = 0; tt < 4; ++tt)
        kf[tt] = *(const bf16x8*)&Ks[tt * 16 + col][(((kc * 4 + quad) ^ col) & 15) * 8];
#pragma unroll
      for (int mt = 0; mt < 2; ++mt)
#pragma unroll
        for (int tt = 0; tt < 4; ++tt)
          s[mt][tt] = __builtin_amdgcn_mfma_f32_16x16x32_bf16(qf[mt][kc], kf[tt], s[mt][tt], 0, 0, 0);
    }

    // ---- online softmax (scores already in log2 domain, scale folded into Q) -----
#pragma unroll
    for (int mt = 0; mt < 2; ++mt)
#pragma unroll
      for (int r = 0; r < 4; ++r) {
        const int qabs = 1024 + qw + mt * 16 + quad * 4 + r;
        float v[4];
#pragma unroll
        for (int tt = 0; tt < 4; ++tt) {
          v[tt] = s[mt][tt][r];
          if (t0 + tt * 16 + col > qabs) v[tt] = -1e30f;
        }
        float mx = fmaxf(fmaxf(v[0], v[1]), fmaxf(v[2], v[3]));
        mx = fmaxf(mx, __shfl_xor(mx, 1));
        mx = fmaxf(mx, __shfl_xor(mx, 2));
        mx = fmaxf(mx, __shfl_xor(mx, 4));
        mx = fmaxf(mx, __shfl_xor(mx, 8));
        const float mnew  = fmaxf(m_r[mt][r], mx);
        const float alpha = fast_exp2(m_r[mt][r] - mnew);
        m_r[mt][r] = mnew;
        float sum = 0.f;
#pragma unroll
        for (int tt = 0; tt < 4; ++tt) {
          v[tt] = fast_exp2(v[tt] - mnew);
          sum += v[tt];
        }
        sum += __shfl_xor(sum, 1);
        sum += __shfl_xor(sum, 2);
        sum += __shfl_xor(sum, 4);
        sum += __shfl_xor(sum, 8);
        l_r[mt][r] = l_r[mt][r] * alpha + sum;
#pragma unroll
        for (int dt = 0; dt < 8; ++dt) o[mt][dt][r] *= alpha;
        // write P (C-layout -> chunk-swizzled LDS for A-operand reads)
        const int prow = mt * 16 + quad * 4 + r;
#pragma unroll
        for (int tt = 0; tt < 4; ++tt) {
          const int t = tt * 16 + col;
          const int c = (t >> 3) ^ (prow & 7);
          Plds[wave][prow][c * 8 + (t & 7)] = f2bf(v[tt]);
        }
      }
    asm volatile("s_waitcnt lgkmcnt(0)" ::: "memory");

    // ---- P fragments + PV --------------------------------------------------------
    bf16x8 pf[2][2];
#pragma unroll
    for (int mt = 0; mt < 2; ++mt)
#pragma unroll
      for (int kk = 0; kk < 2; ++kk)
        pf[mt][kk] = *(const bf16x8*)&Plds[wave][mt * 16 + col][(((kk * 4 + quad) ^ (col & 7))) * 8];
#pragma unroll
    for (int kk = 0; kk < 2; ++kk)
#pragma unroll
      for (int dt = 0; dt < 8; ++dt) {
        bf16x8 vf = *(const bf16x8*)&Vs[dt * 16 + col][(((kk * 4 + quad) ^ (col & 7))) * 8];
#pragma unroll
        for (int mt = 0; mt < 2; ++mt)
          o[mt][dt] = __builtin_amdgcn_mfma_f32_16x16x32_bf16(pf[mt][kk], vf, o[mt][dt], 0, 0, 0);
      }
    __syncthreads();   // Ks/Vs fully consumed before next staging
  }

  // ---- epilogue: normalize + store ctx bf16 (b, s, h, d) --------------------------
  float inv[2][4];
#pragma unroll
  for (int mt = 0; mt < 2; ++mt)
#pragma unroll
    for (int r = 0; r < 4; ++r) inv[mt][r] = 1.0f / l_r[mt][r];
#pragma unroll
  for (int mt = 0; mt < 2; ++mt)
#pragma unroll
    for (int dt = 0; dt < 8; ++dt)
#pragma unroll
      for (int r = 0; r < 4; ++r) {
        const int q = qw + mt * 16 + quad * 4 + r;
        const int d = dt * 16 + col;
        ctx[(size_t)(b * 1024 + q) * 4096 + h * 128 + d] = f2bf(o[mt][dt][r] * inv[mt][r]);
      }
}

// ----------------------------------------------------------------------------------
extern "C" void kernel_launch(void* const* d_in, const int* in_sizes, int n_in,
                              void* d_out, int out_size, void* d_ws, size_t ws_size,
                              hipStream_t stream) {
  const float* x    = (const float*)d_in[0];
  const float* kc   = (const float*)d_in[1];
  const float* vc   = (const float*)d_in[2];
  const float* rope = (const float*)d_in[3];
  const float* Wq   = (const float*)d_in[4];
  const float* Wk   = (const float*)d_in[5];
  const float* Wv   = (const float*)d_in[6];
  const float* Wo   = (const float*)d_in[7];

  float* out = (float*)d_out;                 // (2,1024,4096)
  float* xk  = out + 8388608;                 // (2,32,2048,128)
  float* xv  = out + 25165824;                // (2,32,2048,128)

  char* ws = (char*)d_ws;
  u16*   Xb   = (u16*)(ws + 0);               // x bf16          16,777,216 B
  u16*   Wc   = (u16*)(ws + 16777216);        // Wqkv bf16      100,663,296 B
  u16*   KbB  = (u16*)(ws + 16777216);        //   after GEMM1: K bf16 (b,h,2048,128)
  u16*   VTb  = (u16*)(ws + 50331648);        //   after GEMM1: V^T bf16 (b,h,128,2048)
  float* QKV  = (float*)(ws + 117440512);     // QKV fp32 (2048 x 12288)
  u16*   Wob  = (u16*)(ws + 117440512);       //   after rope: Wo bf16
  u16*   ctxb = (u16*)(ws + 150994944);       //   after rope: ctx bf16
  u16*   Qbb  = (u16*)(ws + 218103808);       // Q bf16 (b,h,1024,128), scale folded

  cvt_f32_bf16<<<8192, 256, 0, stream>>>(x, Xb, 8388608);
  cvt_f32_bf16<<<16384, 256, 0, stream>>>(Wq, Wc, 16777216);
  cvt_f32_bf16<<<16384, 256, 0, stream>>>(Wk, Wc + 16777216, 16777216);
  cvt_f32_bf16<<<16384, 256, 0, stream>>>(Wv, Wc + 33554432, 16777216);
  gemm_bt_256<<<dim3(48, 8), 512, 0, stream>>>(Xb, Wc, QKV, 2048, 12288, 4096);
  rope_q_kernel<<<16384, 256, 0, stream>>>(QKV, rope, Qbb);
  rope_k_kernel<<<16384, 256, 0, stream>>>(QKV, rope, xk, KbB);
  copy_v_kernel<<<32768, 256, 0, stream>>>(QKV, xv);
  cache_copy_k_kernel<<<32768, 256, 0, stream>>>(kc, xk, KbB);
  cache_copy_v_kernel<<<32768, 256, 0, stream>>>(vc, xv);
  transpose_v_kernel<<<dim3(64, 4, 64), 256, 0, stream>>>(xv, VTb);
  cvt_f32_bf16<<<16384, 256, 0, stream>>>(Wo, Wob, 16777216);
  attn_kernel<<<dim3(8, 64), 256, 0, stream>>>(Qbb, KbB, VTb, ctxb);
  gemm_bt<<<dim3(32, 16), 256, 0, stream>>>(ctxb, Wob, out, 2048, 4096, 4096);
}

// Round 6
// 992.839 us; speedup vs baseline: 1.0242x; 1.0104x over previous
//
#include <hip/hip_runtime.h>
#include <cstdint>
#include <cstddef>

typedef unsigned short u16;
typedef __attribute__((ext_vector_type(8))) short bf16x8;   // 8 bf16 = 4 VGPRs
typedef __attribute__((ext_vector_type(4))) float f32x4;    // MFMA 16x16 C/D

using gas_ptr = const __attribute__((address_space(1))) void*;
using las_ptr = __attribute__((address_space(3))) void*;

__device__ __forceinline__ u16 f2bf(float f) {
  union { float f; unsigned int u; } v; v.f = f;
  unsigned int u = v.u;
  return (u16)((u + 0x7fffu + ((u >> 16) & 1u)) >> 16);  // RNE
}

__device__ __forceinline__ float fast_exp2(float x) {
  return __builtin_amdgcn_exp2f(x);   // raw v_exp_f32
}

// ---------------- elementwise fp32 -> bf16 convert (vectorized x4) ----------------
__global__ __launch_bounds__(256) void cvt_f32_bf16(const float* __restrict__ src,
                                                    u16* __restrict__ dst, int n) {
  int i = (blockIdx.x * 256 + threadIdx.x) * 4;
  if (i >= n) return;
  float4 v = *(const float4*)(src + i);
  ushort4 o;
  o.x = f2bf(v.x); o.y = f2bf(v.y); o.z = f2bf(v.z); o.w = f2bf(v.w);
  *(ushort4*)(dst + i) = o;
}

// ---------------- m97-style bf16 GEMM: C[M,N] = A[M,K] * B[N,K]^T (fp32 out) ------
// kept for the Wo GEMM (grid 32x16 = 512 blocks; a 256^2 tile would leave half the
// CUs idle at M=2048,N=4096).
__global__ __launch_bounds__(256) void gemm_bt(const u16* __restrict__ A,
                                               const u16* __restrict__ B,
                                               float* __restrict__ C,
                                               int M, int N, int K) {
  __shared__ u16 As[128][32];
  __shared__ u16 Bs[128][32];
  const int m0 = blockIdx.y * 128, n0 = blockIdx.x * 128;
  const int tid = threadIdx.x;
  const int wave = tid >> 6, lane = tid & 63;
  const int wm = (wave & 1) * 64, wn = (wave >> 1) * 64;
  const int srow = lane >> 2, skoff = (lane & 3) * 8;
  const int col = lane & 15, quad = lane >> 4;
  f32x4 acc[4][4] = {};
  for (int k0 = 0; k0 < K; k0 += 32) {
#pragma unroll
    for (int r = 0; r < 2; ++r) {
      const u16* ga = A + (size_t)(m0 + r * 64 + wave * 16 + srow) * K + k0 + skoff;
      const u16* gb = B + (size_t)(n0 + r * 64 + wave * 16 + srow) * K + k0 + skoff;
      __builtin_amdgcn_global_load_lds((gas_ptr)ga, (las_ptr)&As[r * 64 + wave * 16][0], 16, 0, 0);
      __builtin_amdgcn_global_load_lds((gas_ptr)gb, (las_ptr)&Bs[r * 64 + wave * 16][0], 16, 0, 0);
    }
    __syncthreads();
    bf16x8 af[4], bfr[4];
#pragma unroll
    for (int t = 0; t < 4; ++t) {
      af[t]  = *(const bf16x8*)&As[wm + t * 16 + col][quad * 8];
      bfr[t] = *(const bf16x8*)&Bs[wn + t * 16 + col][quad * 8];
    }
#pragma unroll
    for (int mt = 0; mt < 4; ++mt)
#pragma unroll
      for (int nt = 0; nt < 4; ++nt)
        acc[mt][nt] = __builtin_amdgcn_mfma_f32_16x16x32_bf16(af[mt], bfr[nt], acc[mt][nt], 0, 0, 0);
    __syncthreads();
  }
#pragma unroll
  for (int mt = 0; mt < 4; ++mt)
#pragma unroll
    for (int nt = 0; nt < 4; ++nt)
#pragma unroll
      for (int r = 0; r < 4; ++r) {
        const int row  = m0 + wm + mt * 16 + quad * 4 + r;
        const int ccol = n0 + wn + nt * 16 + col;
        C[(size_t)row * N + ccol] = acc[mt][nt][r];
      }
}

// ---------------- 256x256 8-phase bf16 GEMM (T2+T3+T4+T5), C = A[M,K] * B[N,K]^T --
// Round-5 findings: 2D XCD chunk halved FETCH (420->188 MB) but dur unchanged ->
// NOT bandwidth-bound. Accounting: per-block MFMA efficiency ~50%; ~617 cy/phase
// overhead on top of 620 cy MFMA. Theory: the TWO barriers per phase fully lockstep
// all 8 waves, so ds_read issue + lgkm latency sit on the critical path instead of
// hiding under the co-resident wave's MFMA burst.
// Round-6 change: SINGLE barrier per phase: {ds_read; STAGE; lgkm0; MFMA; [VM]; BAR}.
// Race ledger (verified): (a) every STAGE's target slot had its last reader drained
// at that reader's lgkm0, >=1 phase-ending BAR before the write; same-phase
// read/write slot sets are disjoint for all 8 phases. (b) VM4 precedes the surviving
// BAR, so the cross-wave landing guarantee at barrier-release is unchanged
// (vmcnt ledger: 12 outstanding at each VM4, drains the 8 oldest = the half-tiles
// read in the next 4 phases; prologue 12-load/VM4 and final-iter VM0 re-checked).

#define BAR   __builtin_amdgcn_s_barrier()
#define LGKM0 asm volatile("s_waitcnt lgkmcnt(0)" ::: "memory")
#define VM4   asm volatile("s_waitcnt vmcnt(4)" ::: "memory")
#define VM0   asm volatile("s_waitcnt vmcnt(0)" ::: "memory")

// AB: 0=A,1=B ; G: global base (already offset to block rows) ; H: half ; T: k-tile
#define STAGE(AB, G, H, T)                                                             \
  do {                                                                                 \
    _Pragma("unroll")                                                                  \
    for (int q = 0; q < 2; ++q) {                                                      \
      const int rl = wave * 16 + q * 8 + (lane >> 3);                                  \
      const int sc = (lane & 7) ^ (rl & 7);                                            \
      __builtin_amdgcn_global_load_lds(                                                \
          (gas_ptr)((G) + (size_t)((H) * 128 + rl) * K + (T) * 64 + sc * 8),           \
          (las_ptr)&sm[(T) & 1][AB][H][wave * 16 + q * 8][0], 16, 0, 0);               \
    }                                                                                  \
  } while (0)

#define LDA(DST, BUF, MH)                                                              \
  do {                                                                                 \
    _Pragma("unroll")                                                                  \
    for (int mi = 0; mi < 4; ++mi)                                                     \
      _Pragma("unroll")                                                                \
      for (int kc = 0; kc < 2; ++kc)                                                   \
        DST[mi][kc] = *(const bf16x8*)&sm[BUF][0][wm][(MH) * 64 + mi * 16 + col]       \
                                         [((kc * 4 + quad) ^ (col & 7)) << 3];         \
  } while (0)

#define LDB(BUF, NH)                                                                   \
  do {                                                                                 \
    _Pragma("unroll")                                                                  \
    for (int ni = 0; ni < 2; ++ni)                                                     \
      _Pragma("unroll")                                                                \
      for (int kc = 0; kc < 2; ++kc)                                                   \
        bb[ni][kc] = *(const bf16x8*)&sm[BUF][1][wn >> 1]                              \
                                        [(wn & 1) * 64 + (NH) * 32 + ni * 16 + col]    \
                                        [((kc * 4 + quad) ^ (col & 7)) << 3];          \
  } while (0)

#define MFMA16(MH, NH, AR)                                                             \
  do {                                                                                 \
    __builtin_amdgcn_s_setprio(1);                                                     \
    _Pragma("unroll")                                                                  \
    for (int mi = 0; mi < 4; ++mi)                                                     \
      _Pragma("unroll")                                                                \
      for (int ni = 0; ni < 2; ++ni)                                                   \
        _Pragma("unroll")                                                              \
        for (int kc = 0; kc < 2; ++kc)                                                 \
          acc[(MH) * 4 + mi][(NH) * 2 + ni] = __builtin_amdgcn_mfma_f32_16x16x32_bf16( \
              AR[mi][kc], bb[ni][kc], acc[(MH) * 4 + mi][(NH) * 2 + ni], 0, 0, 0);     \
    __builtin_amdgcn_s_setprio(0);                                                     \
  } while (0)

__global__ __launch_bounds__(512, 2) void gemm_bt_256(const u16* __restrict__ A,
                                                      const u16* __restrict__ B,
                                                      float* __restrict__ C,
                                                      int M, int N, int K) {
  __shared__ u16 sm[2][2][2][128][64];   // [buf][A/B][half][row][k] = 128 KiB
  const int tid  = threadIdx.x;
  const int wave = tid >> 6, lane = tid & 63;
  const int wm   = wave >> 2, wn = wave & 3;
  const int col  = lane & 15, quad = lane >> 4;

  // ---- 2D XCD-chunked block mapping (kept: FETCH 420->188 MB, round-5) ----
  const int bid = blockIdx.y * gridDim.x + blockIdx.x;
  int m_idx, n_idx;
  if (gridDim.x == 48 && gridDim.y == 8) {
    const int x = bid & 7;          // XCD (hardware round-robin on dispatch index)
    const int r = bid >> 3;         // rank within XCD, 0..47
    m_idx = r & 7;                  // column-major within the 8m x 6n chunk
    n_idx = x * 6 + (r >> 3);
  } else {
    m_idx = bid / gridDim.x;
    n_idx = bid % gridDim.x;
  }
  const int m0 = m_idx * 256;
  const int n0 = n_idx * 256;

  const u16* Ag = A + (size_t)m0 * K;
  const u16* Bg = B + (size_t)n0 * K;

  f32x4 acc[8][4] = {};
  bf16x8 a0[4][2], a1[4][2], bb[2][2];

  // prologue: tile0 (A0,A1,B0,B1 -> buf0) + tile1 A halves (-> buf1) = 12 loads/lane
  STAGE(0, Ag, 0, 0); STAGE(0, Ag, 1, 0);
  STAGE(1, Bg, 0, 0); STAGE(1, Bg, 1, 0);
  STAGE(0, Ag, 0, 1); STAGE(0, Ag, 1, 1);
  VM4;   // tile0 landed; tile1 A halves may stay in flight
  BAR;

  const int NIT = K >> 7;   // K / 128 (2 tiles per iteration)
  for (int i = 0; i < NIT - 1; ++i) {
    const int t0 = i * 2;
    // ---- ph1 (m0,n0) on buf0 / tile t0 ----
    LDA(a0, 0, 0); LDB(0, 0); STAGE(1, Bg, 0, t0 + 1);
    LGKM0; MFMA16(0, 0, a0); BAR;
    // ---- ph2 (m1,n0) ----
    LDA(a1, 0, 1); STAGE(1, Bg, 1, t0 + 1);
    LGKM0; MFMA16(1, 0, a1); BAR;
    // ---- ph3 (m1,n1) ----
    LDB(0, 1); STAGE(0, Ag, 0, t0 + 2);
    LGKM0; MFMA16(1, 1, a1); BAR;
    // ---- ph4 (m0,n1): no ds_reads (a0,bb retained) ----
    STAGE(0, Ag, 1, t0 + 2);
    LGKM0; MFMA16(0, 1, a0); VM4; BAR;
    // ---- ph5 (m0,n0) on buf1 / tile t0+1 ----
    LDA(a0, 1, 0); LDB(1, 0); STAGE(1, Bg, 0, t0 + 2);
    LGKM0; MFMA16(0, 0, a0); BAR;
    // ---- ph6 (m1,n0) ----
    LDA(a1, 1, 1); STAGE(1, Bg, 1, t0 + 2);
    LGKM0; MFMA16(1, 0, a1); BAR;
    // ---- ph7 (m1,n1) ----
    LDB(1, 1); STAGE(0, Ag, 0, t0 + 3);
    LGKM0; MFMA16(1, 1, a1); BAR;
    // ---- ph8 (m0,n1) ----
    STAGE(0, Ag, 1, t0 + 3);
    LGKM0; MFMA16(0, 1, a0); VM4; BAR;
  }
  // ---- last iteration: only the final tile's B halves still need staging --------
  {
    const int t0 = 2 * NIT - 2;
    LDA(a0, 0, 0); LDB(0, 0); STAGE(1, Bg, 0, t0 + 1);
    LGKM0; MFMA16(0, 0, a0); BAR;
    LDA(a1, 0, 1); STAGE(1, Bg, 1, t0 + 1);
    LGKM0; MFMA16(1, 0, a1); BAR;
    LDB(0, 1);
    LGKM0; MFMA16(1, 1, a1); BAR;
    LGKM0; MFMA16(0, 1, a0); VM0; BAR;
    LDA(a0, 1, 0); LDB(1, 0);
    LGKM0; MFMA16(0, 0, a0); BAR;
    LDA(a1, 1, 1);
    LGKM0; MFMA16(1, 0, a1); BAR;
    LDB(1, 1);
    LGKM0; MFMA16(1, 1, a1); BAR;
    LGKM0; MFMA16(0, 1, a0);
  }

  // ---- epilogue: fp32 C store --------------------------------------------------
#pragma unroll
  for (int mi = 0; mi < 8; ++mi)
#pragma unroll
    for (int ni = 0; ni < 4; ++ni)
#pragma unroll
      for (int r = 0; r < 4; ++r) {
        const int row = m0 + wm * 128 + mi * 16 + quad * 4 + r;
        const int cc  = n0 + wn * 64 + ni * 16 + col;
        C[(size_t)row * N + cc] = acc[mi][ni][r];
      }
}

#undef STAGE
#undef LDA
#undef LDB
#undef MFMA16
#undef BAR
#undef LGKM0
#undef VM4
#undef VM0

// ---------------- RoPE on Q (scale*log2e folded): QKV32 fp32 -> Qb bf16 -----------
__global__ __launch_bounds__(256) void rope_q_kernel(const float* __restrict__ qkv,
                                                     const float* __restrict__ rope,
                                                     u16* __restrict__ Qb) {
  const float qs = 0.08838834764831845f * 1.4426950408889634f;  // 1/sqrt(128) * log2(e)
  int idx = blockIdx.x * 256 + threadIdx.x;           // (bh, s, pair) : 64*1024*64
  int i = idx & 63, s = (idx >> 6) & 1023, bh = idx >> 16;
  int b = bh >> 5, h = bh & 31;
  const float* p = qkv + (size_t)(b * 1024 + s) * 12288 + h * 128 + 2 * i;
  float t0 = p[0], t1 = p[1];
  float c = rope[(s * 64 + i) * 2], sn = rope[(s * 64 + i) * 2 + 1];
  size_t o = ((size_t)bh * 1024 + s) * 128 + 2 * i;
  Qb[o]     = f2bf((t0 * c - t1 * sn) * qs);
  Qb[o + 1] = f2bf((t0 * sn + t1 * c) * qs);
}

// ---------------- RoPE on K: fp32 -> xk (d_out) AND Kb bf16, positions >= 1024 ----
__global__ __launch_bounds__(256) void rope_k_kernel(const float* __restrict__ qkv,
                                                     const float* __restrict__ rope,
                                                     float* __restrict__ xk,
                                                     u16* __restrict__ Kb) {
  int idx = blockIdx.x * 256 + threadIdx.x;
  int i = idx & 63, s = (idx >> 6) & 1023, bh = idx >> 16;
  int b = bh >> 5, h = bh & 31;
  const float* p = qkv + (size_t)(b * 1024 + s) * 12288 + 4096 + h * 128 + 2 * i;
  float t0 = p[0], t1 = p[1];
  float c = rope[(s * 64 + i) * 2], sn = rope[(s * 64 + i) * 2 + 1];
  float r0 = t0 * c - t1 * sn, r1 = t0 * sn + t1 * c;
  size_t o = ((size_t)bh * 2048 + 1024 + s) * 128 + 2 * i;
  xk[o] = r0; xk[o + 1] = r1;
  Kb[o] = f2bf(r0); Kb[o + 1] = f2bf(r1);
}

// ---------------- V new positions: fp32 -> xv (d_out), positions >= 1024 ----------
__global__ __launch_bounds__(256) void copy_v_kernel(const float* __restrict__ qkv,
                                                     float* __restrict__ xv) {
  int idx = blockIdx.x * 256 + threadIdx.x;           // (bh, s, d) : 64*1024*128
  int d = idx & 127, s = (idx >> 7) & 1023, bh = idx >> 17;
  int b = bh >> 5, h = bh & 31;
  xv[((size_t)bh * 2048 + 1024 + s) * 128 + d] =
      qkv[(size_t)(b * 1024 + s) * 12288 + 8192 + h * 128 + d];
}

// ---------------- K cache: fp32 -> xk fp32 + Kb bf16 at t < 1024 ------------------
__global__ __launch_bounds__(256) void cache_copy_k_kernel(const float* __restrict__ src,
                                                           float* __restrict__ dst,
                                                           u16* __restrict__ dstb) {
  int idx = blockIdx.x * 256 + threadIdx.x;           // 64*1024*128
  int d = idx & 127, t = (idx >> 7) & 1023, bh = idx >> 17;
  float v = src[idx];
  size_t o = ((size_t)bh * 2048 + t) * 128 + d;
  dst[o] = v;
  dstb[o] = f2bf(v);
}

// ---------------- V cache: fp32 -> xv fp32 at t < 1024 ----------------------------
__global__ __launch_bounds__(256) void cache_copy_v_kernel(const float* __restrict__ src,
                                                           float* __restrict__ dst) {
  int idx = blockIdx.x * 256 + threadIdx.x;
  int d = idx & 127, t = (idx >> 7) & 1023, bh = idx >> 17;
  dst[((size_t)bh * 2048 + t) * 128 + d] = src[idx];
}

// ---------------- transpose: xv fp32 (bh, 2048 t, 128 d) -> VT bf16 (bh, 128 d, 2048 t)
__global__ __launch_bounds__(256) void transpose_v_kernel(const float* __restrict__ src,
                                                          u16* __restrict__ dst) {
  __shared__ float tile[32][33];
  int bh = blockIdx.z;
  int t0 = blockIdx.x * 32, d0 = blockIdx.y * 32;
  int tx = threadIdx.x & 31, ty = threadIdx.x >> 5;
  const float* s = src + ((size_t)bh * 2048 + t0) * 128 + d0;
#pragma unroll
  for (int i = 0; i < 4; ++i)
    tile[ty + i * 8][tx] = s[(ty + i * 8) * 128 + tx];
  __syncthreads();
  u16* dp = dst + ((size_t)bh * 128 + d0) * 2048 + t0;
#pragma unroll
  for (int i = 0; i < 4; ++i)
    dp[(ty + i * 8) * 2048 + tx] = f2bf(tile[tx][ty + i * 8]);
}

// ---------------- flash attention v2: 1 block = (bh, 128 q rows), LDS K/V staging --
// wave handles 32 q rows (2 m-tiles of 16); t-step = 64; K/V XOR-swizzled in LDS.
__global__ __launch_bounds__(256, 2) void attn_kernel(const u16* __restrict__ Qb,
                                                      const u16* __restrict__ Kb,
                                                      const u16* __restrict__ VT,
                                                      u16* __restrict__ ctx) {
  const int bh = blockIdx.y;
  const int b = bh >> 5, h = bh & 31;
  const int wave = threadIdx.x >> 6, lane = threadIdx.x & 63;
  const int col = lane & 15, quad = lane >> 4;
  const int qblk = blockIdx.x * 128;
  const int qw = qblk + wave * 32;          // this wave's 32 q rows

  __shared__ u16 Ks[64][128];   // (t, d), chunk-XOR-swizzled: 16 KB
  __shared__ u16 Vs[128][64];   // (d, t), chunk-XOR-swizzled: 16 KB
  __shared__ u16 Plds[4][32][64];  // per-wave P, chunk-XOR-swizzled: 16 KB

  const u16* Qh = Qb + (size_t)bh * 1024 * 128;
  const u16* Kh = Kb + (size_t)bh * 2048 * 128;
  const u16* Vh = VT + (size_t)bh * 128 * 2048;

  // Q fragments: A-operand layout (m = col, k = quad*8 + j within kc*32)
  bf16x8 qf[2][4];
#pragma unroll
  for (int mt = 0; mt < 2; ++mt)
#pragma unroll
    for (int kc = 0; kc < 4; ++kc)
      qf[mt][kc] = *(const bf16x8*)&Qh[(size_t)(qw + mt * 16 + col) * 128 + kc * 32 + quad * 8];

  f32x4 o[2][8] = {};
  float m_r[2][4], l_r[2][4];
#pragma unroll
  for (int mt = 0; mt < 2; ++mt)
#pragma unroll
    for (int r = 0; r < 4; ++r) { m_r[mt][r] = -1e30f; l_r[mt][r] = 0.0f; }

  const int t_end = 1024 + qblk + 128;

  for (int t0 = 0; t0 < t_end; t0 += 64) {
    // ---- stage K tile (64 t x 128 d): 4 issues x 4 waves x (4 rows, 16 chunks) ----
#pragma unroll
    for (int j = 0; j < 4; ++j) {
      const int g = j * 4 + wave;
      const int r = g * 4 + (lane >> 4);              // t row 0..63
      const int cg = (lane & 15) ^ (r & 15);          // source chunk (16B) for XOR swizzle
      __builtin_amdgcn_global_load_lds((gas_ptr)(Kh + (size_t)(t0 + r) * 128 + cg * 8),
                                       (las_ptr)&Ks[g * 4][0], 16, 0, 0);
    }
    // ---- stage V^T tile (128 d x 64 t): 4 issues x 4 waves x (8 rows, 8 chunks) ---
#pragma unroll
    for (int j = 0; j < 4; ++j) {
      const int g = j * 4 + wave;
      const int r = g * 8 + (lane >> 3);              // d row 0..127
      const int cg = (lane & 7) ^ (r & 7);
      __builtin_amdgcn_global_load_lds((gas_ptr)(Vh + (size_t)r * 2048 + t0 + cg * 8),
                                       (las_ptr)&Vs[g * 8][0], 16, 0, 0);
    }
    __syncthreads();

    // ---- QK^T: S[2 mt][4 tt] over K=128 -----------------------------------------
    f32x4 s[2][4];
#pragma unroll
    for (int mt = 0; mt < 2; ++mt)
#pragma unroll
      for (int tt = 0; tt < 4; ++tt) s[mt][tt] = (f32x4){0.f, 0.f, 0.f, 0.f};
#pragma unroll
    for (int kc = 0; kc < 4; ++kc) {
      bf16x8 kf[4];
#pragma unroll
      for (int tt = 0; tt < 4; ++tt)
        kf[tt] = *(const bf16x8*)&Ks[tt * 16 + col][(((kc * 4 + quad) ^ col) & 15) * 8];
#pragma unroll
      for (int mt = 0; mt < 2; ++mt)
#pragma unroll
        for (int tt = 0; tt < 4; ++tt)
          s[mt][tt] = __builtin_amdgcn_mfma_f32_16x16x32_bf16(qf[mt][kc], kf[tt], s[mt][tt], 0, 0, 0);
    }

    // ---- online softmax (scores already in log2 domain, scale folded into Q) -----
#pragma unroll
    for (int mt = 0; mt < 2; ++mt)
#pragma unroll
      for (int r = 0; r < 4; ++r) {
        const int qabs = 1024 + qw + mt * 16 + quad * 4 + r;
        float v[4];
#pragma unroll
        for (int tt = 0; tt < 4; ++tt) {
          v[tt] = s[mt][tt][r];
          if (t0 + tt * 16 + col > qabs) v[tt] = -1e30f;
        }
        float mx = fmaxf(fmaxf(v[0], v[1]), fmaxf(v[2], v[3]));
        mx = fmaxf(mx, __shfl_xor(mx, 1));
        mx = fmaxf(mx, __shfl_xor(mx, 2));
        mx = fmaxf(mx, __shfl_xor(mx, 4));
        mx = fmaxf(mx, __shfl_xor(mx, 8));
        const float mnew  = fmaxf(m_r[mt][r], mx);
        const float alpha = fast_exp2(m_r[mt][r] - mnew);
        m_r[mt][r] = mnew;
        float sum = 0.f;
#pragma unroll
        for (int tt = 0; tt < 4; ++tt) {
          v[tt] = fast_exp2(v[tt] - mnew);
          sum += v[tt];
        }
        sum += __shfl_xor(sum, 1);
        sum += __shfl_xor(sum, 2);
        sum += __shfl_xor(sum, 4);
        sum += __shfl_xor(sum, 8);
        l_r[mt][r] = l_r[mt][r] * alpha + sum;
#pragma unroll
        for (int dt = 0; dt < 8; ++dt) o[mt][dt][r] *= alpha;
        // write P (C-layout -> chunk-swizzled LDS for A-operand reads)
        const int prow = mt * 16 + quad * 4 + r;
#pragma unroll
        for (int tt = 0; tt < 4; ++tt) {
          const int t = tt * 16 + col;
          const int c = (t >> 3) ^ (prow & 7);
          Plds[wave][prow][c * 8 + (t & 7)] = f2bf(v[tt]);
        }
      }
    asm volatile("s_waitcnt lgkmcnt(0)" ::: "memory");

    // ---- P fragments + PV --------------------------------------------------------
    bf16x8 pf[2][2];
#pragma unroll
    for (int mt = 0; mt < 2; ++mt)
#pragma unroll
      for (int kk = 0; kk < 2; ++kk)
        pf[mt][kk] = *(const bf16x8*)&Plds[wave][mt * 16 + col][(((kk * 4 + quad) ^ (col & 7))) * 8];
#pragma unroll
    for (int kk = 0; kk < 2; ++kk)
#pragma unroll
      for (int dt = 0; dt < 8; ++dt) {
        bf16x8 vf = *(const bf16x8*)&Vs[dt * 16 + col][(((kk * 4 + quad) ^ (col & 7))) * 8];
#pragma unroll
        for (int mt = 0; mt < 2; ++mt)
          o[mt][dt] = __builtin_amdgcn_mfma_f32_16x16x32_bf16(pf[mt][kk], vf, o[mt][dt], 0, 0, 0);
      }
    __syncthreads();   // Ks/Vs fully consumed before next staging
  }

  // ---- epilogue: normalize + store ctx bf16 (b, s, h, d) --------------------------
  float inv[2][4];
#pragma unroll
  for (int mt = 0; mt < 2; ++mt)
#pragma unroll
    for (int r = 0; r < 4; ++r) inv[mt][r] = 1.0f / l_r[mt][r];
#pragma unroll
  for (int mt = 0; mt < 2; ++mt)
#pragma unroll
    for (int dt = 0; dt < 8; ++dt)
#pragma unroll
      for (int r = 0; r < 4; ++r) {
        const int q = qw + mt * 16 + quad * 4 + r;
        const int d = dt * 16 + col;
        ctx[(size_t)(b * 1024 + q) * 4096 + h * 128 + d] = f2bf(o[mt][dt][r] * inv[mt][r]);
      }
}

// ----------------------------------------------------------------------------------
extern "C" void kernel_launch(void* const* d_in, const int* in_sizes, int n_in,
                              void* d_out, int out_size, void* d_ws, size_t ws_size,
                              hipStream_t stream) {
  const float* x    = (const float*)d_in[0];
  const float* kc   = (const float*)d_in[1];
  const float* vc   = (const float*)d_in[2];
  const float* rope = (const float*)d_in[3];
  const float* Wq   = (const float*)d_in[4];
  const float* Wk   = (const float*)d_in[5];
  const float* Wv   = (const float*)d_in[6];
  const float* Wo   = (const float*)d_in[7];

  float* out = (float*)d_out;                 // (2,1024,4096)
  float* xk  = out + 8388608;                 // (2,32,2048,128)
  float* xv  = out + 25165824;                // (2,32,2048,128)

  char* ws = (char*)d_ws;
  u16*   Xb   = (u16*)(ws + 0);               // x bf16          16,777,216 B
  u16*   Wc   = (u16*)(ws + 16777216);        // Wqkv bf16      100,663,296 B
  u16*   KbB  = (u16*)(ws + 16777216);        //   after GEMM1: K bf16 (b,h,2048,128)
  u16*   VTb  = (u16*)(ws + 50331648);        //   after GEMM1: V^T bf16 (b,h,128,2048)
  float* QKV  = (float*)(ws + 117440512);     // QKV fp32 (2048 x 12288)
  u16*   Wob  = (u16*)(ws + 117440512);       //   after rope: Wo bf16
  u16*   ctxb = (u16*)(ws + 150994944);       //   after rope: ctx bf16
  u16*   Qbb  = (u16*)(ws + 218103808);       // Q bf16 (b,h,1024,128), scale folded

  cvt_f32_bf16<<<8192, 256, 0, stream>>>(x, Xb, 8388608);
  cvt_f32_bf16<<<16384, 256, 0, stream>>>(Wq, Wc, 16777216);
  cvt_f32_bf16<<<16384, 256, 0, stream>>>(Wk, Wc + 16777216, 16777216);
  cvt_f32_bf16<<<16384, 256, 0, stream>>>(Wv, Wc + 33554432, 16777216);
  gemm_bt_256<<<dim3(48, 8), 512, 0, stream>>>(Xb, Wc, QKV, 2048, 12288, 4096);
  rope_q_kernel<<<16384, 256, 0, stream>>>(QKV, rope, Qbb);
  rope_k_kernel<<<16384, 256, 0, stream>>>(QKV, rope, xk, KbB);
  copy_v_kernel<<<32768, 256, 0, stream>>>(QKV, xv);
  cache_copy_k_kernel<<<32768, 256, 0, stream>>>(kc, xk, KbB);
  cache_copy_v_kernel<<<32768, 256, 0, stream>>>(vc, xv);
  transpose_v_kernel<<<dim3(64, 4, 64), 256, 0, stream>>>(xv, VTb);
  cvt_f32_bf16<<<16384, 256, 0, stream>>>(Wo, Wob, 16777216);
  attn_kernel<<<dim3(8, 64), 256, 0, stream>>>(Qbb, KbB, VTb, ctxb);
  gemm_bt<<<dim3(32, 16), 256, 0, stream>>>(ctxb, Wob, out, 2048, 4096, 4096);
}

// Round 8
// 984.494 us; speedup vs baseline: 1.0329x; 1.0085x over previous
//
#include <hip/hip_runtime.h>
#include <cstdint>
#include <cstddef>

typedef unsigned short u16;
typedef __attribute__((ext_vector_type(8))) short bf16x8;   // 8 bf16 = 4 VGPRs
typedef __attribute__((ext_vector_type(4))) float f32x4;    // MFMA 16x16 C/D

using gas_ptr = const __attribute__((address_space(1))) void*;
using las_ptr = __attribute__((address_space(3))) void*;

__device__ __forceinline__ u16 f2bf(float f) {
  union { float f; unsigned int u; } v; v.f = f;
  unsigned int u = v.u;
  return (u16)((u + 0x7fffu + ((u >> 16) & 1u)) >> 16);  // RNE
}

__device__ __forceinline__ float fast_exp2(float x) {
  return __builtin_amdgcn_exp2f(x);   // raw v_exp_f32
}

// ---------------- elementwise fp32 -> bf16 convert (vectorized x4) ----------------
__global__ __launch_bounds__(256) void cvt_f32_bf16(const float* __restrict__ src,
                                                    u16* __restrict__ dst, int n) {
  int i = (blockIdx.x * 256 + threadIdx.x) * 4;
  if (i >= n) return;
  float4 v = *(const float4*)(src + i);
  ushort4 o;
  o.x = f2bf(v.x); o.y = f2bf(v.y); o.z = f2bf(v.z); o.w = f2bf(v.w);
  *(ushort4*)(dst + i) = o;
}

// ---------------- fused convert of Wq|Wk|Wv -> contiguous Wc bf16 ------------------
__global__ __launch_bounds__(256) void cvt3_w(const float* __restrict__ Wq,
                                              const float* __restrict__ Wk,
                                              const float* __restrict__ Wv,
                                              u16* __restrict__ dst) {
  int i = (blockIdx.x * 256 + threadIdx.x) * 4;   // i < 50331648
  const float* src; int off;
  if (i < 16777216)      { src = Wq; off = i; }
  else if (i < 33554432) { src = Wk; off = i - 16777216; }
  else                   { src = Wv; off = i - 33554432; }
  float4 v = *(const float4*)(src + off);
  ushort4 o;
  o.x = f2bf(v.x); o.y = f2bf(v.y); o.z = f2bf(v.z); o.w = f2bf(v.w);
  *(ushort4*)(dst + i) = o;
}

// ---------------- m97-style bf16 GEMM: C[M,N] = A[M,K] * B[N,K]^T (fp32 out) ------
// kept for the Wo GEMM (grid 32x16 = 512 blocks).
__global__ __launch_bounds__(256) void gemm_bt(const u16* __restrict__ A,
                                               const u16* __restrict__ B,
                                               float* __restrict__ C,
                                               int M, int N, int K) {
  __shared__ u16 As[128][32];
  __shared__ u16 Bs[128][32];
  const int m0 = blockIdx.y * 128, n0 = blockIdx.x * 128;
  const int tid = threadIdx.x;
  const int wave = tid >> 6, lane = tid & 63;
  const int wm = (wave & 1) * 64, wn = (wave >> 1) * 64;
  const int srow = lane >> 2, skoff = (lane & 3) * 8;
  const int col = lane & 15, quad = lane >> 4;
  f32x4 acc[4][4] = {};
  for (int k0 = 0; k0 < K; k0 += 32) {
#pragma unroll
    for (int r = 0; r < 2; ++r) {
      const u16* ga = A + (size_t)(m0 + r * 64 + wave * 16 + srow) * K + k0 + skoff;
      const u16* gb = B + (size_t)(n0 + r * 64 + wave * 16 + srow) * K + k0 + skoff;
      __builtin_amdgcn_global_load_lds((gas_ptr)ga, (las_ptr)&As[r * 64 + wave * 16][0], 16, 0, 0);
      __builtin_amdgcn_global_load_lds((gas_ptr)gb, (las_ptr)&Bs[r * 64 + wave * 16][0], 16, 0, 0);
    }
    __syncthreads();
    bf16x8 af[4], bfr[4];
#pragma unroll
    for (int t = 0; t < 4; ++t) {
      af[t]  = *(const bf16x8*)&As[wm + t * 16 + col][quad * 8];
      bfr[t] = *(const bf16x8*)&Bs[wn + t * 16 + col][quad * 8];
    }
#pragma unroll
    for (int mt = 0; mt < 4; ++mt)
#pragma unroll
      for (int nt = 0; nt < 4; ++nt)
        acc[mt][nt] = __builtin_amdgcn_mfma_f32_16x16x32_bf16(af[mt], bfr[nt], acc[mt][nt], 0, 0, 0);
    __syncthreads();
  }
#pragma unroll
  for (int mt = 0; mt < 4; ++mt)
#pragma unroll
    for (int nt = 0; nt < 4; ++nt)
#pragma unroll
      for (int r = 0; r < 4; ++r) {
        const int row  = m0 + wm + mt * 16 + quad * 4 + r;
        const int ccol = n0 + wn + nt * 16 + col;
        C[(size_t)row * N + ccol] = acc[mt][nt][r];
      }
}

// ---------------- 256x256 8-phase bf16 QKV GEMM with FUSED RoPE epilogue -----------
// K-loop = round-6 verified core (single barrier/phase, vmcnt(4), 2D XCD chunk).
// Round-7 change: instead of writing QKV fp32 (100 MB) and re-reading it in 3
// elementwise kernels (200 MB more), the epilogue applies RoPE in-register and
// writes the final forms directly:
//   n0 < 4096  (Q): rope -> Qb bf16 (scale*log2e folded), layout (bh,1024,128)
//   n0 < 8192  (K): rope -> xk fp32 + Kb bf16 at positions t>=1024
//   else       (V): copy -> xv fp32 at positions t>=1024
// RoPE pairing: lane pairs (xor 1) hold adjacent d columns -> __shfl_xor(v,1).
// kind is block-uniform (Q/K/V boundaries are tile-aligned). fp32 math identical
// to the removed rope kernels (same expressions on the same acc values).

#define BAR   __builtin_amdgcn_s_barrier()
#define LGKM0 asm volatile("s_waitcnt lgkmcnt(0)" ::: "memory")
#define VM4   asm volatile("s_waitcnt vmcnt(4)" ::: "memory")
#define VM0   asm volatile("s_waitcnt vmcnt(0)" ::: "memory")

// AB: 0=A,1=B ; G: global base (already offset to block rows) ; H: half ; T: k-tile
#define STAGE(AB, G, H, T)                                                             \
  do {                                                                                 \
    _Pragma("unroll")                                                                  \
    for (int q = 0; q < 2; ++q) {                                                      \
      const int rl = wave * 16 + q * 8 + (lane >> 3);                                  \
      const int sc = (lane & 7) ^ (rl & 7);                                            \
      __builtin_amdgcn_global_load_lds(                                                \
          (gas_ptr)((G) + (size_t)((H) * 128 + rl) * K + (T) * 64 + sc * 8),           \
          (las_ptr)&sm[(T) & 1][AB][H][wave * 16 + q * 8][0], 16, 0, 0);               \
    }                                                                                  \
  } while (0)

#define LDA(DST, BUF, MH)                                                              \
  do {                                                                                 \
    _Pragma("unroll")                                                                  \
    for (int mi = 0; mi < 4; ++mi)                                                     \
      _Pragma("unroll")                                                                \
      for (int kc = 0; kc < 2; ++kc)                                                   \
        DST[mi][kc] = *(const bf16x8*)&sm[BUF][0][wm][(MH) * 64 + mi * 16 + col]       \
                                         [((kc * 4 + quad) ^ (col & 7)) << 3];         \
  } while (0)

#define LDB(BUF, NH)                                                                   \
  do {                                                                                 \
    _Pragma("unroll")                                                                  \
    for (int ni = 0; ni < 2; ++ni)                                                     \
      _Pragma("unroll")                                                                \
      for (int kc = 0; kc < 2; ++kc)                                                   \
        bb[ni][kc] = *(const bf16x8*)&sm[BUF][1][wn >> 1]                              \
                                        [(wn & 1) * 64 + (NH) * 32 + ni * 16 + col]    \
                                        [((kc * 4 + quad) ^ (col & 7)) << 3];          \
  } while (0)

#define MFMA16(MH, NH, AR)                                                             \
  do {                                                                                 \
    __builtin_amdgcn_s_setprio(1);                                                     \
    _Pragma("unroll")                                                                  \
    for (int mi = 0; mi < 4; ++mi)                                                     \
      _Pragma("unroll")                                                                \
      for (int ni = 0; ni < 2; ++ni)                                                   \
        _Pragma("unroll")                                                              \
        for (int kc = 0; kc < 2; ++kc)                                                 \
          acc[(MH) * 4 + mi][(NH) * 2 + ni] = __builtin_amdgcn_mfma_f32_16x16x32_bf16( \
              AR[mi][kc], bb[ni][kc], acc[(MH) * 4 + mi][(NH) * 2 + ni], 0, 0, 0);     \
    __builtin_amdgcn_s_setprio(0);                                                     \
  } while (0)

__global__ __launch_bounds__(512, 2) void gemm_qkv(const u16* __restrict__ A,
                                                   const u16* __restrict__ B,
                                                   const float* __restrict__ rope,
                                                   u16* __restrict__ Qb,
                                                   float* __restrict__ xk,
                                                   u16* __restrict__ Kb,
                                                   float* __restrict__ xv,
                                                   int M, int N, int K) {
  __shared__ u16 sm[2][2][2][128][64];   // [buf][A/B][half][row][k] = 128 KiB
  const int tid  = threadIdx.x;
  const int wave = tid >> 6, lane = tid & 63;
  const int wm   = wave >> 2, wn = wave & 3;
  const int col  = lane & 15, quad = lane >> 4;

  // ---- 2D XCD-chunked block mapping (FETCH 420->188 MB, round-5) ----
  const int bid = blockIdx.y * gridDim.x + blockIdx.x;
  int m_idx, n_idx;
  if (gridDim.x == 48 && gridDim.y == 8) {
    const int x = bid & 7;          // XCD (hardware round-robin on dispatch index)
    const int r = bid >> 3;         // rank within XCD, 0..47
    m_idx = r & 7;                  // column-major within the 8m x 6n chunk
    n_idx = x * 6 + (r >> 3);
  } else {
    m_idx = bid / gridDim.x;
    n_idx = bid % gridDim.x;
  }
  const int m0 = m_idx * 256;
  const int n0 = n_idx * 256;

  const u16* Ag = A + (size_t)m0 * K;
  const u16* Bg = B + (size_t)n0 * K;

  f32x4 acc[8][4] = {};
  bf16x8 a0[4][2], a1[4][2], bb[2][2];

  // prologue: tile0 (A0,A1,B0,B1 -> buf0) + tile1 A halves (-> buf1) = 12 loads/lane
  STAGE(0, Ag, 0, 0); STAGE(0, Ag, 1, 0);
  STAGE(1, Bg, 0, 0); STAGE(1, Bg, 1, 0);
  STAGE(0, Ag, 0, 1); STAGE(0, Ag, 1, 1);
  VM4;   // tile0 landed; tile1 A halves may stay in flight
  BAR;

  const int NIT = K >> 7;   // K / 128 (2 tiles per iteration)
  for (int i = 0; i < NIT - 1; ++i) {
    const int t0 = i * 2;
    // ---- ph1 (m0,n0) on buf0 / tile t0 ----
    LDA(a0, 0, 0); LDB(0, 0); STAGE(1, Bg, 0, t0 + 1);
    LGKM0; MFMA16(0, 0, a0); BAR;
    // ---- ph2 (m1,n0) ----
    LDA(a1, 0, 1); STAGE(1, Bg, 1, t0 + 1);
    LGKM0; MFMA16(1, 0, a1); BAR;
    // ---- ph3 (m1,n1) ----
    LDB(0, 1); STAGE(0, Ag, 0, t0 + 2);
    LGKM0; MFMA16(1, 1, a1); BAR;
    // ---- ph4 (m0,n1): no ds_reads (a0,bb retained) ----
    STAGE(0, Ag, 1, t0 + 2);
    LGKM0; MFMA16(0, 1, a0); VM4; BAR;
    // ---- ph5 (m0,n0) on buf1 / tile t0+1 ----
    LDA(a0, 1, 0); LDB(1, 0); STAGE(1, Bg, 0, t0 + 2);
    LGKM0; MFMA16(0, 0, a0); BAR;
    // ---- ph6 (m1,n0) ----
    LDA(a1, 1, 1); STAGE(1, Bg, 1, t0 + 2);
    LGKM0; MFMA16(1, 0, a1); BAR;
    // ---- ph7 (m1,n1) ----
    LDB(1, 1); STAGE(0, Ag, 0, t0 + 3);
    LGKM0; MFMA16(1, 1, a1); BAR;
    // ---- ph8 (m0,n1) ----
    STAGE(0, Ag, 1, t0 + 3);
    LGKM0; MFMA16(0, 1, a0); VM4; BAR;
  }
  // ---- last iteration: only the final tile's B halves still need staging --------
  {
    const int t0 = 2 * NIT - 2;
    LDA(a0, 0, 0); LDB(0, 0); STAGE(1, Bg, 0, t0 + 1);
    LGKM0; MFMA16(0, 0, a0); BAR;
    LDA(a1, 0, 1); STAGE(1, Bg, 1, t0 + 1);
    LGKM0; MFMA16(1, 0, a1); BAR;
    LDB(0, 1);
    LGKM0; MFMA16(1, 1, a1); BAR;
    LGKM0; MFMA16(0, 1, a0); VM0; BAR;
    LDA(a0, 1, 0); LDB(1, 0);
    LGKM0; MFMA16(0, 0, a0); BAR;
    LDA(a1, 1, 1);
    LGKM0; MFMA16(1, 0, a1); BAR;
    LDB(1, 1);
    LGKM0; MFMA16(1, 1, a1); BAR;
    LGKM0; MFMA16(0, 1, a0);
  }

  // ---- fused epilogue: RoPE + direct Q/K/V stores -------------------------------
  const float qs = 0.08838834764831845f * 1.4426950408889634f;  // 1/sqrt(128)*log2(e)
  const int kind = n0 >> 12;          // 0=Q, 1=K, 2=V (block-uniform)
  const int colb = n0 + wn * 64 + (lane & 15);
#pragma unroll
  for (int mi = 0; mi < 8; ++mi)
#pragma unroll
    for (int ni = 0; ni < 4; ++ni)
#pragma unroll
      for (int r = 0; r < 4; ++r) {
        const int row = m0 + wm * 128 + mi * 16 + quad * 4 + r;
        const int b_ = row >> 10, s = row & 1023;
        const int cc = colb + ni * 16;
        float v = acc[mi][ni][r];
        if (kind == 2) {
          const int c2 = cc - 8192;
          xv[((size_t)(b_ * 32 + (c2 >> 7)) * 2048 + 1024 + s) * 128 + (c2 & 127)] = v;
        } else {
          const float partner = __shfl_xor(v, 1);
          const int c2 = cc & 4095, d = c2 & 127, h = c2 >> 7;
          const int ri = (s * 64 + (d >> 1)) * 2;
          const float cz = rope[ri], sn = rope[ri + 1];
          const float ov = (d & 1) ? (partner * sn + v * cz) : (v * cz - partner * sn);
          if (kind == 0) {
            Qb[((size_t)(b_ * 32 + h) * 1024 + s) * 128 + d] = f2bf(ov * qs);
          } else {
            const size_t o = ((size_t)(b_ * 32 + h) * 2048 + 1024 + s) * 128 + d;
            xk[o] = ov; Kb[o] = f2bf(ov);
          }
        }
      }
}

#undef STAGE
#undef LDA
#undef LDB
#undef MFMA16
#undef BAR
#undef LGKM0
#undef VM4
#undef VM0

// ---------------- cache copy (merged K+V): fp32 -> xk/xv fp32 + Kb bf16, t<1024 ---
__global__ __launch_bounds__(256) void cache_copy_kernel(const float* __restrict__ kc,
                                                         const float* __restrict__ vc,
                                                         float* __restrict__ xk,
                                                         float* __restrict__ xv,
                                                         u16* __restrict__ Kb) {
  int idx = blockIdx.x * 256 + threadIdx.x;           // 64*1024*128
  int d = idx & 127, t = (idx >> 7) & 1023, bh = idx >> 17;
  size_t o = ((size_t)bh * 2048 + t) * 128 + d;
  float k = kc[idx], v = vc[idx];
  xk[o] = k; Kb[o] = f2bf(k);
  xv[o] = v;
}

// ---------------- transpose: xv fp32 (bh, 2048 t, 128 d) -> VT bf16 (bh, 128 d, 2048 t)
__global__ __launch_bounds__(256) void transpose_v_kernel(const float* __restrict__ src,
                                                          u16* __restrict__ dst) {
  __shared__ float tile[32][33];
  int bh = blockIdx.z;
  int t0 = blockIdx.x * 32, d0 = blockIdx.y * 32;
  int tx = threadIdx.x & 31, ty = threadIdx.x >> 5;
  const float* s = src + ((size_t)bh * 2048 + t0) * 128 + d0;
#pragma unroll
  for (int i = 0; i < 4; ++i)
    tile[ty + i * 8][tx] = s[(ty + i * 8) * 128 + tx];
  __syncthreads();
  u16* dp = dst + ((size_t)bh * 128 + d0) * 2048 + t0;
#pragma unroll
  for (int i = 0; i < 4; ++i)
    dp[(ty + i * 8) * 2048 + tx] = f2bf(tile[tx][ty + i * 8]);
}

// ---------------- flash attention v2: 1 block = (bh, 128 q rows), LDS K/V staging --
__global__ __launch_bounds__(256, 2) void attn_kernel(const u16* __restrict__ Qb,
                                                      const u16* __restrict__ Kb,
                                                      const u16* __restrict__ VT,
                                                      u16* __restrict__ ctx) {
  const int bh = blockIdx.y;
  const int b = bh >> 5, h = bh & 31;
  const int wave = threadIdx.x >> 6, lane = threadIdx.x & 63;
  const int col = lane & 15, quad = lane >> 4;
  const int qblk = blockIdx.x * 128;
  const int qw = qblk + wave * 32;          // this wave's 32 q rows

  __shared__ u16 Ks[64][128];   // (t, d), chunk-XOR-swizzled: 16 KB
  __shared__ u16 Vs[128][64];   // (d, t), chunk-XOR-swizzled: 16 KB
  __shared__ u16 Plds[4][32][64];  // per-wave P, chunk-XOR-swizzled: 16 KB

  const u16* Qh = Qb + (size_t)bh * 1024 * 128;
  const u16* Kh = Kb + (size_t)bh * 2048 * 128;
  const u16* Vh = VT + (size_t)bh * 128 * 2048;

  // Q fragments: A-operand layout (m = col, k = quad*8 + j within kc*32)
  bf16x8 qf[2][4];
#pragma unroll
  for (int mt = 0; mt < 2; ++mt)
#pragma unroll
    for (int kc = 0; kc < 4; ++kc)
      qf[mt][kc] = *(const bf16x8*)&Qh[(size_t)(qw + mt * 16 + col) * 128 + kc * 32 + quad * 8];

  f32x4 o[2][8] = {};
  float m_r[2][4], l_r[2][4];
#pragma unroll
  for (int mt = 0; mt < 2; ++mt)
#pragma unroll
    for (int r = 0; r < 4; ++r) { m_r[mt][r] = -1e30f; l_r[mt][r] = 0.0f; }

  const int t_end = 1024 + qblk + 128;

  for (int t0 = 0; t0 < t_end; t0 += 64) {
    // ---- stage K tile (64 t x 128 d) ----
#pragma unroll
    for (int j = 0; j < 4; ++j) {
      const int g = j * 4 + wave;
      const int r = g * 4 + (lane >> 4);              // t row 0..63
      const int cg = (lane & 15) ^ (r & 15);          // source chunk (16B) for XOR swizzle
      __builtin_amdgcn_global_load_lds((gas_ptr)(Kh + (size_t)(t0 + r) * 128 + cg * 8),
                                       (las_ptr)&Ks[g * 4][0], 16, 0, 0);
    }
    // ---- stage V^T tile (128 d x 64 t) ----
#pragma unroll
    for (int j = 0; j < 4; ++j) {
      const int g = j * 4 + wave;
      const int r = g * 8 + (lane >> 3);              // d row 0..127
      const int cg = (lane & 7) ^ (r & 7);
      __builtin_amdgcn_global_load_lds((gas_ptr)(Vh + (size_t)r * 2048 + t0 + cg * 8),
                                       (las_ptr)&Vs[g * 8][0], 16, 0, 0);
    }
    __syncthreads();

    // ---- QK^T: S[2 mt][4 tt] over K=128 -----------------------------------------
    f32x4 s[2][4];
#pragma unroll
    for (int mt = 0; mt < 2; ++mt)
#pragma unroll
      for (int tt = 0; tt < 4; ++tt) s[mt][tt] = (f32x4){0.f, 0.f, 0.f, 0.f};
#pragma unroll
    for (int kc = 0; kc < 4; ++kc) {
      bf16x8 kf[4];
#pragma unroll
      for (int tt = 0; tt < 4; ++tt)
        kf[tt] = *(const bf16x8*)&Ks[tt * 16 + col][(((kc * 4 + quad) ^ col) & 15) * 8];
#pragma unroll
      for (int mt = 0; mt < 2; ++mt)
#pragma unroll
        for (int tt = 0; tt < 4; ++tt)
          s[mt][tt] = __builtin_amdgcn_mfma_f32_16x16x32_bf16(qf[mt][kc], kf[tt], s[mt][tt], 0, 0, 0);
    }

    // ---- online softmax (log2 domain, scale folded into Q) ----------------------
#pragma unroll
    for (int mt = 0; mt < 2; ++mt)
#pragma unroll
      for (int r = 0; r < 4; ++r) {
        const int qabs = 1024 + qw + mt * 16 + quad * 4 + r;
        float v[4];
#pragma unroll
        for (int tt = 0; tt < 4; ++tt) {
          v[tt] = s[mt][tt][r];
          if (t0 + tt * 16 + col > qabs) v[tt] = -1e30f;
        }
        float mx = fmaxf(fmaxf(v[0], v[1]), fmaxf(v[2], v[3]));
        mx = fmaxf(mx, __shfl_xor(mx, 1));
        mx = fmaxf(mx, __shfl_xor(mx, 2));
        mx = fmaxf(mx, __shfl_xor(mx, 4));
        mx = fmaxf(mx, __shfl_xor(mx, 8));
        const float mnew  = fmaxf(m_r[mt][r], mx);
        const float alpha = fast_exp2(m_r[mt][r] - mnew);
        m_r[mt][r] = mnew;
        float sum = 0.f;
#pragma unroll
        for (int tt = 0; tt < 4; ++tt) {
          v[tt] = fast_exp2(v[tt] - mnew);
          sum += v[tt];
        }
        sum += __shfl_xor(sum, 1);
        sum += __shfl_xor(sum, 2);
        sum += __shfl_xor(sum, 4);
        sum += __shfl_xor(sum, 8);
        l_r[mt][r] = l_r[mt][r] * alpha + sum;
#pragma unroll
        for (int dt = 0; dt < 8; ++dt) o[mt][dt][r] *= alpha;
        const int prow = mt * 16 + quad * 4 + r;
#pragma unroll
        for (int tt = 0; tt < 4; ++tt) {
          const int t = tt * 16 + col;
          const int c = (t >> 3) ^ (prow & 7);
          Plds[wave][prow][c * 8 + (t & 7)] = f2bf(v[tt]);
        }
      }
    asm volatile("s_waitcnt lgkmcnt(0)" ::: "memory");

    // ---- P fragments + PV --------------------------------------------------------
    bf16x8 pf[2][2];
#pragma unroll
    for (int mt = 0; mt < 2; ++mt)
#pragma unroll
      for (int kk = 0; kk < 2; ++kk)
        pf[mt][kk] = *(const bf16x8*)&Plds[wave][mt * 16 + col][(((kk * 4 + quad) ^ (col & 7))) * 8];
#pragma unroll
    for (int kk = 0; kk < 2; ++kk)
#pragma unroll
      for (int dt = 0; dt < 8; ++dt) {
        bf16x8 vf = *(const bf16x8*)&Vs[dt * 16 + col][(((kk * 4 + quad) ^ (col & 7))) * 8];
#pragma unroll
        for (int mt = 0; mt < 2; ++mt)
          o[mt][dt] = __builtin_amdgcn_mfma_f32_16x16x32_bf16(pf[mt][kk], vf, o[mt][dt], 0, 0, 0);
      }
    __syncthreads();   // Ks/Vs fully consumed before next staging
  }

  // ---- epilogue: normalize + store ctx bf16 (b, s, h, d) --------------------------
  float inv[2][4];
#pragma unroll
  for (int mt = 0; mt < 2; ++mt)
#pragma unroll
    for (int r = 0; r < 4; ++r) inv[mt][r] = 1.0f / l_r[mt][r];
#pragma unroll
  for (int mt = 0; mt < 2; ++mt)
#pragma unroll
    for (int dt = 0; dt < 8; ++dt)
#pragma unroll
      for (int r = 0; r < 4; ++r) {
        const int q = qw + mt * 16 + quad * 4 + r;
        const int d = dt * 16 + col;
        ctx[(size_t)(b * 1024 + q) * 4096 + h * 128 + d] = f2bf(o[mt][dt][r] * inv[mt][r]);
      }
}

// ----------------------------------------------------------------------------------
extern "C" void kernel_launch(void* const* d_in, const int* in_sizes, int n_in,
                              void* d_out, int out_size, void* d_ws, size_t ws_size,
                              hipStream_t stream) {
  const float* x    = (const float*)d_in[0];
  const float* kc   = (const float*)d_in[1];
  const float* vc   = (const float*)d_in[2];
  const float* rope = (const float*)d_in[3];
  const float* Wq   = (const float*)d_in[4];
  const float* Wk   = (const float*)d_in[5];
  const float* Wv   = (const float*)d_in[6];
  const float* Wo   = (const float*)d_in[7];

  float* out = (float*)d_out;                 // (2,1024,4096)
  float* xk  = out + 8388608;                 // (2,32,2048,128)
  float* xv  = out + 25165824;                // (2,32,2048,128)

  char* ws = (char*)d_ws;
  u16*   Xb   = (u16*)(ws + 0);               // x bf16                16,777,216 B
  u16*   Wc   = (u16*)(ws + 16777216);        // Wqkv bf16 [16.7M,117.4M)
  u16*   VTb  = (u16*)(ws + 50331648);        //   after GEMM1: V^T bf16 (overlaps Wk ok)
  u16*   Wob  = (u16*)(ws + 117440512);       // Wo bf16   [117.4M,151.0M)
  u16*   ctxb = (u16*)(ws + 150994944);       // ctx bf16  [151.0M,184.5M)
  u16*   KbB  = (u16*)(ws + 184549376);       // K bf16 (b,h,2048,128) [184.5M,218.1M)
  u16*   Qbb  = (u16*)(ws + 218103808);       // Q bf16 (b,h,1024,128), scale folded

  cvt_f32_bf16<<<8192, 256, 0, stream>>>(x, Xb, 8388608);
  cvt3_w<<<49152, 256, 0, stream>>>(Wq, Wk, Wv, Wc);
  gemm_qkv<<<dim3(48, 8), 512, 0, stream>>>(Xb, Wc, rope, Qbb, xk, KbB, xv,
                                            2048, 12288, 4096);
  cache_copy_kernel<<<32768, 256, 0, stream>>>(kc, vc, xk, xv, KbB);
  transpose_v_kernel<<<dim3(64, 4, 64), 256, 0, stream>>>(xv, VTb);
  cvt_f32_bf16<<<16384, 256, 0, stream>>>(Wo, Wob, 16777216);
  attn_kernel<<<dim3(8, 64), 256, 0, stream>>>(Qbb, KbB, VTb, ctxb);
  gemm_bt<<<dim3(32, 16), 256, 0, stream>>>(ctxb, Wob, out, 2048, 4096, 4096);
}

// Round 9
// 944.015 us; speedup vs baseline: 1.0772x; 1.0429x over previous
//
#include <hip/hip_runtime.h>
#include <cstdint>
#include <cstddef>

typedef unsigned short u16;
typedef __attribute__((ext_vector_type(8))) short bf16x8;   // 8 bf16 = 4 VGPRs
typedef __attribute__((ext_vector_type(4))) float f32x4;    // MFMA 16x16 C/D

using gas_ptr = const __attribute__((address_space(1))) void*;
using las_ptr = __attribute__((address_space(3))) void*;

__device__ __forceinline__ u16 f2bf(float f) {
  union { float f; unsigned int u; } v; v.f = f;
  unsigned int u = v.u;
  return (u16)((u + 0x7fffu + ((u >> 16) & 1u)) >> 16);  // RNE
}

__device__ __forceinline__ float fast_exp2(float x) {
  return __builtin_amdgcn_exp2f(x);   // raw v_exp_f32
}

// ---------------- elementwise fp32 -> bf16 convert (vectorized x4) ----------------
__global__ __launch_bounds__(256) void cvt_f32_bf16(const float* __restrict__ src,
                                                    u16* __restrict__ dst, int n) {
  int i = (blockIdx.x * 256 + threadIdx.x) * 4;
  if (i >= n) return;
  float4 v = *(const float4*)(src + i);
  ushort4 o;
  o.x = f2bf(v.x); o.y = f2bf(v.y); o.z = f2bf(v.z); o.w = f2bf(v.w);
  *(ushort4*)(dst + i) = o;
}

// ---------------- fused convert of Wq|Wk|Wv -> contiguous Wc bf16 ------------------
__global__ __launch_bounds__(256) void cvt3_w(const float* __restrict__ Wq,
                                              const float* __restrict__ Wk,
                                              const float* __restrict__ Wv,
                                              u16* __restrict__ dst) {
  int i = (blockIdx.x * 256 + threadIdx.x) * 4;   // i < 50331648
  const float* src; int off;
  if (i < 16777216)      { src = Wq; off = i; }
  else if (i < 33554432) { src = Wk; off = i - 16777216; }
  else                   { src = Wv; off = i - 33554432; }
  float4 v = *(const float4*)(src + off);
  ushort4 o;
  o.x = f2bf(v.x); o.y = f2bf(v.y); o.z = f2bf(v.z); o.w = f2bf(v.w);
  *(ushort4*)(dst + i) = o;
}

// ---------------- m97-style bf16 GEMM: C[M,N] = A[M,K] * B[N,K]^T (fp32 out) ------
// kept for the Wo GEMM (grid 32x16 = 512 blocks).
__global__ __launch_bounds__(256) void gemm_bt(const u16* __restrict__ A,
                                               const u16* __restrict__ B,
                                               float* __restrict__ C,
                                               int M, int N, int K) {
  __shared__ u16 As[128][32];
  __shared__ u16 Bs[128][32];
  const int m0 = blockIdx.y * 128, n0 = blockIdx.x * 128;
  const int tid = threadIdx.x;
  const int wave = tid >> 6, lane = tid & 63;
  const int wm = (wave & 1) * 64, wn = (wave >> 1) * 64;
  const int srow = lane >> 2, skoff = (lane & 3) * 8;
  const int col = lane & 15, quad = lane >> 4;
  f32x4 acc[4][4] = {};
  for (int k0 = 0; k0 < K; k0 += 32) {
#pragma unroll
    for (int r = 0; r < 2; ++r) {
      const u16* ga = A + (size_t)(m0 + r * 64 + wave * 16 + srow) * K + k0 + skoff;
      const u16* gb = B + (size_t)(n0 + r * 64 + wave * 16 + srow) * K + k0 + skoff;
      __builtin_amdgcn_global_load_lds((gas_ptr)ga, (las_ptr)&As[r * 64 + wave * 16][0], 16, 0, 0);
      __builtin_amdgcn_global_load_lds((gas_ptr)gb, (las_ptr)&Bs[r * 64 + wave * 16][0], 16, 0, 0);
    }
    __syncthreads();
    bf16x8 af[4], bfr[4];
#pragma unroll
    for (int t = 0; t < 4; ++t) {
      af[t]  = *(const bf16x8*)&As[wm + t * 16 + col][quad * 8];
      bfr[t] = *(const bf16x8*)&Bs[wn + t * 16 + col][quad * 8];
    }
#pragma unroll
    for (int mt = 0; mt < 4; ++mt)
#pragma unroll
      for (int nt = 0; nt < 4; ++nt)
        acc[mt][nt] = __builtin_amdgcn_mfma_f32_16x16x32_bf16(af[mt], bfr[nt], acc[mt][nt], 0, 0, 0);
    __syncthreads();
  }
#pragma unroll
  for (int mt = 0; mt < 4; ++mt)
#pragma unroll
    for (int nt = 0; nt < 4; ++nt)
#pragma unroll
      for (int r = 0; r < 4; ++r) {
        const int row  = m0 + wm + mt * 16 + quad * 4 + r;
        const int ccol = n0 + wn + nt * 16 + col;
        C[(size_t)row * N + ccol] = acc[mt][nt][r];
      }
}

// ---------------- 256x256 8-phase bf16 QKV GEMM with FUSED RoPE epilogue -----------
// K-loop = round-6 verified core (single barrier/phase, vmcnt(4), 2D XCD chunk).
// Round-9 change: LDS-STAGED epilogue. Round-8's direct epilogue cost +64us: u16
// scalar stores made 32B half-line segments per quad, K-blocks doubled store count,
// plus 128 shfl_xor + 256 scalar rope loads per thread. Fix: after the K-loop's
// final barrier sm is dead (all ds_reads drained before it); reuse as per-wave
// scratch (16 x 68-padded fp32). Stage each mi-fragment, read back 4 CONSECUTIVE
// cols per lane (ds_read_b128). RoPE pairs are then in-lane (no shfl), rope fetch
// is one float4 (lanes 0-15 = 256B contiguous), stores vectorized: Q ushort4
// (128B/quad-row), K float4+ushort4 (256B+128B), V float4 (256B). fp32 expressions
// keep identical operand order -> same absmax.

#define BAR   __builtin_amdgcn_s_barrier()
#define LGKM0 asm volatile("s_waitcnt lgkmcnt(0)" ::: "memory")
#define VM4   asm volatile("s_waitcnt vmcnt(4)" ::: "memory")
#define VM0   asm volatile("s_waitcnt vmcnt(0)" ::: "memory")

// AB: 0=A,1=B ; G: global base (already offset to block rows) ; H: half ; T: k-tile
#define STAGE(AB, G, H, T)                                                             \
  do {                                                                                 \
    _Pragma("unroll")                                                                  \
    for (int q = 0; q < 2; ++q) {                                                      \
      const int rl = wave * 16 + q * 8 + (lane >> 3);                                  \
      const int sc = (lane & 7) ^ (rl & 7);                                            \
      __builtin_amdgcn_global_load_lds(                                                \
          (gas_ptr)((G) + (size_t)((H) * 128 + rl) * K + (T) * 64 + sc * 8),           \
          (las_ptr)&sm[(T) & 1][AB][H][wave * 16 + q * 8][0], 16, 0, 0);               \
    }                                                                                  \
  } while (0)

#define LDA(DST, BUF, MH)                                                              \
  do {                                                                                 \
    _Pragma("unroll")                                                                  \
    for (int mi = 0; mi < 4; ++mi)                                                     \
      _Pragma("unroll")                                                                \
      for (int kc = 0; kc < 2; ++kc)                                                   \
        DST[mi][kc] = *(const bf16x8*)&sm[BUF][0][wm][(MH) * 64 + mi * 16 + col]       \
                                         [((kc * 4 + quad) ^ (col & 7)) << 3];         \
  } while (0)

#define LDB(BUF, NH)                                                                   \
  do {                                                                                 \
    _Pragma("unroll")                                                                  \
    for (int ni = 0; ni < 2; ++ni)                                                     \
      _Pragma("unroll")                                                                \
      for (int kc = 0; kc < 2; ++kc)                                                   \
        bb[ni][kc] = *(const bf16x8*)&sm[BUF][1][wn >> 1]                              \
                                        [(wn & 1) * 64 + (NH) * 32 + ni * 16 + col]    \
                                        [((kc * 4 + quad) ^ (col & 7)) << 3];          \
  } while (0)

#define MFMA16(MH, NH, AR)                                                             \
  do {                                                                                 \
    __builtin_amdgcn_s_setprio(1);                                                     \
    _Pragma("unroll")                                                                  \
    for (int mi = 0; mi < 4; ++mi)                                                     \
      _Pragma("unroll")                                                                \
      for (int ni = 0; ni < 2; ++ni)                                                   \
        _Pragma("unroll")                                                              \
        for (int kc = 0; kc < 2; ++kc)                                                 \
          acc[(MH) * 4 + mi][(NH) * 2 + ni] = __builtin_amdgcn_mfma_f32_16x16x32_bf16( \
              AR[mi][kc], bb[ni][kc], acc[(MH) * 4 + mi][(NH) * 2 + ni], 0, 0, 0);     \
    __builtin_amdgcn_s_setprio(0);                                                     \
  } while (0)

__global__ __launch_bounds__(512, 2) void gemm_qkv(const u16* __restrict__ A,
                                                   const u16* __restrict__ B,
                                                   const float* __restrict__ rope,
                                                   u16* __restrict__ Qb,
                                                   float* __restrict__ xk,
                                                   u16* __restrict__ Kb,
                                                   float* __restrict__ xv,
                                                   int M, int N, int K) {
  __shared__ __align__(16) u16 sm[2][2][2][128][64];   // [buf][A/B][half][row][k] = 128 KiB
  const int tid  = threadIdx.x;
  const int wave = tid >> 6, lane = tid & 63;
  const int wm   = wave >> 2, wn = wave & 3;
  const int col  = lane & 15, quad = lane >> 4;

  // ---- 2D XCD-chunked block mapping (FETCH 420->188 MB, round-5) ----
  const int bid = blockIdx.y * gridDim.x + blockIdx.x;
  int m_idx, n_idx;
  if (gridDim.x == 48 && gridDim.y == 8) {
    const int x = bid & 7;          // XCD (hardware round-robin on dispatch index)
    const int r = bid >> 3;         // rank within XCD, 0..47
    m_idx = r & 7;                  // column-major within the 8m x 6n chunk
    n_idx = x * 6 + (r >> 3);
  } else {
    m_idx = bid / gridDim.x;
    n_idx = bid % gridDim.x;
  }
  const int m0 = m_idx * 256;
  const int n0 = n_idx * 256;

  const u16* Ag = A + (size_t)m0 * K;
  const u16* Bg = B + (size_t)n0 * K;

  f32x4 acc[8][4] = {};
  bf16x8 a0[4][2], a1[4][2], bb[2][2];

  // prologue: tile0 (A0,A1,B0,B1 -> buf0) + tile1 A halves (-> buf1) = 12 loads/lane
  STAGE(0, Ag, 0, 0); STAGE(0, Ag, 1, 0);
  STAGE(1, Bg, 0, 0); STAGE(1, Bg, 1, 0);
  STAGE(0, Ag, 0, 1); STAGE(0, Ag, 1, 1);
  VM4;   // tile0 landed; tile1 A halves may stay in flight
  BAR;

  const int NIT = K >> 7;   // K / 128 (2 tiles per iteration)
  for (int i = 0; i < NIT - 1; ++i) {
    const int t0 = i * 2;
    // ---- ph1 (m0,n0) on buf0 / tile t0 ----
    LDA(a0, 0, 0); LDB(0, 0); STAGE(1, Bg, 0, t0 + 1);
    LGKM0; MFMA16(0, 0, a0); BAR;
    // ---- ph2 (m1,n0) ----
    LDA(a1, 0, 1); STAGE(1, Bg, 1, t0 + 1);
    LGKM0; MFMA16(1, 0, a1); BAR;
    // ---- ph3 (m1,n1) ----
    LDB(0, 1); STAGE(0, Ag, 0, t0 + 2);
    LGKM0; MFMA16(1, 1, a1); BAR;
    // ---- ph4 (m0,n1): no ds_reads (a0,bb retained) ----
    STAGE(0, Ag, 1, t0 + 2);
    LGKM0; MFMA16(0, 1, a0); VM4; BAR;
    // ---- ph5 (m0,n0) on buf1 / tile t0+1 ----
    LDA(a0, 1, 0); LDB(1, 0); STAGE(1, Bg, 0, t0 + 2);
    LGKM0; MFMA16(0, 0, a0); BAR;
    // ---- ph6 (m1,n0) ----
    LDA(a1, 1, 1); STAGE(1, Bg, 1, t0 + 2);
    LGKM0; MFMA16(1, 0, a1); BAR;
    // ---- ph7 (m1,n1) ----
    LDB(1, 1); STAGE(0, Ag, 0, t0 + 3);
    LGKM0; MFMA16(1, 1, a1); BAR;
    // ---- ph8 (m0,n1) ----
    STAGE(0, Ag, 1, t0 + 3);
    LGKM0; MFMA16(0, 1, a0); VM4; BAR;
  }
  // ---- last iteration: only the final tile's B halves still need staging --------
  {
    const int t0 = 2 * NIT - 2;
    LDA(a0, 0, 0); LDB(0, 0); STAGE(1, Bg, 0, t0 + 1);
    LGKM0; MFMA16(0, 0, a0); BAR;
    LDA(a1, 0, 1); STAGE(1, Bg, 1, t0 + 1);
    LGKM0; MFMA16(1, 0, a1); BAR;
    LDB(0, 1);
    LGKM0; MFMA16(1, 1, a1); BAR;
    LGKM0; MFMA16(0, 1, a0); VM0; BAR;
    LDA(a0, 1, 0); LDB(1, 0);
    LGKM0; MFMA16(0, 0, a0); BAR;
    LDA(a1, 1, 1);
    LGKM0; MFMA16(1, 0, a1); BAR;
    LDB(1, 1);
    LGKM0; MFMA16(1, 1, a1); BAR;   // after this BAR all waves' LDS reads are done
    LGKM0; MFMA16(0, 1, a0);
  }

  // ---- fused epilogue v2: LDS-staged, vectorized + coalesced stores -------------
  const float qs = 0.08838834764831845f * 1.4426950408889634f;  // 1/sqrt(128)*log2(e)
  const int kind = n0 >> 12;          // 0=Q, 1=K, 2=V (block-uniform)
  float* scr = (float*)&sm[0][0][0][0][0] + wave * (16 * 68);   // 4352 B/wave, 16B-aligned
  const int rrow = lane >> 4;          // readback row-in-group 0..3
  const int c0   = (lane & 15) * 4;    // 4 consecutive cols per lane
#pragma unroll
  for (int mi = 0; mi < 8; ++mi) {
#pragma unroll
    for (int ni = 0; ni < 4; ++ni)
#pragma unroll
      for (int r = 0; r < 4; ++r)
        scr[(quad * 4 + r) * 68 + ni * 16 + col] = acc[mi][ni][r];
    // same-wave DS pipe is in-order: reads below see the writes above.
#pragma unroll
    for (int j = 0; j < 4; ++j) {
      const int row = j * 4 + rrow;                          // 0..15
      const float4 vv = *(const float4*)&scr[row * 68 + c0];
      const int gr = m0 + wm * 128 + mi * 16 + row;          // global output row
      const int b_ = gr >> 10, s = gr & 1023;
      const int cc = n0 + wn * 64 + c0;                      // 4 consecutive cols
      if (kind == 2) {
        const int c2 = cc - 8192;
        *(float4*)&xv[((size_t)(b_ * 32 + (c2 >> 7)) * 2048 + 1024 + s) * 128 + (c2 & 127)] = vv;
      } else {
        const int c2 = cc & 4095, d0 = c2 & 127, h = c2 >> 7;
        const float4 rv = *(const float4*)&rope[(s * 64 + (d0 >> 1)) * 2];
        const float e0 = vv.x * rv.x - vv.y * rv.y;
        const float e1 = vv.x * rv.y + vv.y * rv.x;
        const float e2 = vv.z * rv.z - vv.w * rv.w;
        const float e3 = vv.z * rv.w + vv.w * rv.z;
        if (kind == 0) {
          ushort4 ov;
          ov.x = f2bf(e0 * qs); ov.y = f2bf(e1 * qs);
          ov.z = f2bf(e2 * qs); ov.w = f2bf(e3 * qs);
          *(ushort4*)&Qb[((size_t)(b_ * 32 + h) * 1024 + s) * 128 + d0] = ov;
        } else {
          const size_t o = ((size_t)(b_ * 32 + h) * 2048 + 1024 + s) * 128 + d0;
          float4 ev; ev.x = e0; ev.y = e1; ev.z = e2; ev.w = e3;
          *(float4*)&xk[o] = ev;
          ushort4 ov;
          ov.x = f2bf(e0); ov.y = f2bf(e1); ov.z = f2bf(e2); ov.w = f2bf(e3);
          *(ushort4*)&Kb[o] = ov;
        }
      }
    }
  }
}

#undef STAGE
#undef LDA
#undef LDB
#undef MFMA16
#undef BAR
#undef LGKM0
#undef VM4
#undef VM0

// ---------------- cache copy (merged K+V): fp32 -> xk/xv fp32 + Kb bf16, t<1024 ---
__global__ __launch_bounds__(256) void cache_copy_kernel(const float* __restrict__ kc,
                                                         const float* __restrict__ vc,
                                                         float* __restrict__ xk,
                                                         float* __restrict__ xv,
                                                         u16* __restrict__ Kb) {
  int idx = blockIdx.x * 256 + threadIdx.x;           // 64*1024*128
  int d = idx & 127, t = (idx >> 7) & 1023, bh = idx >> 17;
  size_t o = ((size_t)bh * 2048 + t) * 128 + d;
  float k = kc[idx], v = vc[idx];
  xk[o] = k; Kb[o] = f2bf(k);
  xv[o] = v;
}

// ---------------- transpose: xv fp32 (bh, 2048 t, 128 d) -> VT bf16 (bh, 128 d, 2048 t)
__global__ __launch_bounds__(256) void transpose_v_kernel(const float* __restrict__ src,
                                                          u16* __restrict__ dst) {
  __shared__ float tile[32][33];
  int bh = blockIdx.z;
  int t0 = blockIdx.x * 32, d0 = blockIdx.y * 32;
  int tx = threadIdx.x & 31, ty = threadIdx.x >> 5;
  const float* s = src + ((size_t)bh * 2048 + t0) * 128 + d0;
#pragma unroll
  for (int i = 0; i < 4; ++i)
    tile[ty + i * 8][tx] = s[(ty + i * 8) * 128 + tx];
  __syncthreads();
  u16* dp = dst + ((size_t)bh * 128 + d0) * 2048 + t0;
#pragma unroll
  for (int i = 0; i < 4; ++i)
    dp[(ty + i * 8) * 2048 + tx] = f2bf(tile[tx][ty + i * 8]);
}

// ---------------- flash attention v2: 1 block = (bh, 128 q rows), LDS K/V staging --
__global__ __launch_bounds__(256, 2) void attn_kernel(const u16* __restrict__ Qb,
                                                      const u16* __restrict__ Kb,
                                                      const u16* __restrict__ VT,
                                                      u16* __restrict__ ctx) {
  const int bh = blockIdx.y;
  const int b = bh >> 5, h = bh & 31;
  const int wave = threadIdx.x >> 6, lane = threadIdx.x & 63;
  const int col = lane & 15, quad = lane >> 4;
  const int qblk = blockIdx.x * 128;
  const int qw = qblk + wave * 32;          // this wave's 32 q rows

  __shared__ u16 Ks[64][128];   // (t, d), chunk-XOR-swizzled: 16 KB
  __shared__ u16 Vs[128][64];   // (d, t), chunk-XOR-swizzled: 16 KB
  __shared__ u16 Plds[4][32][64];  // per-wave P, chunk-XOR-swizzled: 16 KB

  const u16* Qh = Qb + (size_t)bh * 1024 * 128;
  const u16* Kh = Kb + (size_t)bh * 2048 * 128;
  const u16* Vh = VT + (size_t)bh * 128 * 2048;

  // Q fragments: A-operand layout (m = col, k = quad*8 + j within kc*32)
  bf16x8 qf[2][4];
#pragma unroll
  for (int mt = 0; mt < 2; ++mt)
#pragma unroll
    for (int kc = 0; kc < 4; ++kc)
      qf[mt][kc] = *(const bf16x8*)&Qh[(size_t)(qw + mt * 16 + col) * 128 + kc * 32 + quad * 8];

  f32x4 o[2][8] = {};
  float m_r[2][4], l_r[2][4];
#pragma unroll
  for (int mt = 0; mt < 2; ++mt)
#pragma unroll
    for (int r = 0; r < 4; ++r) { m_r[mt][r] = -1e30f; l_r[mt][r] = 0.0f; }

  const int t_end = 1024 + qblk + 128;

  for (int t0 = 0; t0 < t_end; t0 += 64) {
    // ---- stage K tile (64 t x 128 d) ----
#pragma unroll
    for (int j = 0; j < 4; ++j) {
      const int g = j * 4 + wave;
      const int r = g * 4 + (lane >> 4);              // t row 0..63
      const int cg = (lane & 15) ^ (r & 15);          // source chunk (16B) for XOR swizzle
      __builtin_amdgcn_global_load_lds((gas_ptr)(Kh + (size_t)(t0 + r) * 128 + cg * 8),
                                       (las_ptr)&Ks[g * 4][0], 16, 0, 0);
    }
    // ---- stage V^T tile (128 d x 64 t) ----
#pragma unroll
    for (int j = 0; j < 4; ++j) {
      const int g = j * 4 + wave;
      const int r = g * 8 + (lane >> 3);              // d row 0..127
      const int cg = (lane & 7) ^ (r & 7);
      __builtin_amdgcn_global_load_lds((gas_ptr)(Vh + (size_t)r * 2048 + t0 + cg * 8),
                                       (las_ptr)&Vs[g * 8][0], 16, 0, 0);
    }
    __syncthreads();

    // ---- QK^T: S[2 mt][4 tt] over K=128 -----------------------------------------
    f32x4 s[2][4];
#pragma unroll
    for (int mt = 0; mt < 2; ++mt)
#pragma unroll
      for (int tt = 0; tt < 4; ++tt) s[mt][tt] = (f32x4){0.f, 0.f, 0.f, 0.f};
#pragma unroll
    for (int kc = 0; kc < 4; ++kc) {
      bf16x8 kf[4];
#pragma unroll
      for (int tt = 0; tt < 4; ++tt)
        kf[tt] = *(const bf16x8*)&Ks[tt * 16 + col][(((kc * 4 + quad) ^ col) & 15) * 8];
#pragma unroll
      for (int mt = 0; mt < 2; ++mt)
#pragma unroll
        for (int tt = 0; tt < 4; ++tt)
          s[mt][tt] = __builtin_amdgcn_mfma_f32_16x16x32_bf16(qf[mt][kc], kf[tt], s[mt][tt], 0, 0, 0);
    }

    // ---- online softmax (log2 domain, scale folded into Q) ----------------------
#pragma unroll
    for (int mt = 0; mt < 2; ++mt)
#pragma unroll
      for (int r = 0; r < 4; ++r) {
        const int qabs = 1024 + qw + mt * 16 + quad * 4 + r;
        float v[4];
#pragma unroll
        for (int tt = 0; tt < 4; ++tt) {
          v[tt] = s[mt][tt][r];
          if (t0 + tt * 16 + col > qabs) v[tt] = -1e30f;
        }
        float mx = fmaxf(fmaxf(v[0], v[1]), fmaxf(v[2], v[3]));
        mx = fmaxf(mx, __shfl_xor(mx, 1));
        mx = fmaxf(mx, __shfl_xor(mx, 2));
        mx = fmaxf(mx, __shfl_xor(mx, 4));
        mx = fmaxf(mx, __shfl_xor(mx, 8));
        const float mnew  = fmaxf(m_r[mt][r], mx);
        const float alpha = fast_exp2(m_r[mt][r] - mnew);
        m_r[mt][r] = mnew;
        float sum = 0.f;
#pragma unroll
        for (int tt = 0; tt < 4; ++tt) {
          v[tt] = fast_exp2(v[tt] - mnew);
          sum += v[tt];
        }
        sum += __shfl_xor(sum, 1);
        sum += __shfl_xor(sum, 2);
        sum += __shfl_xor(sum, 4);
        sum += __shfl_xor(sum, 8);
        l_r[mt][r] = l_r[mt][r] * alpha + sum;
#pragma unroll
        for (int dt = 0; dt < 8; ++dt) o[mt][dt][r] *= alpha;
        const int prow = mt * 16 + quad * 4 + r;
#pragma unroll
        for (int tt = 0; tt < 4; ++tt) {
          const int t = tt * 16 + col;
          const int c = (t >> 3) ^ (prow & 7);
          Plds[wave][prow][c * 8 + (t & 7)] = f2bf(v[tt]);
        }
      }
    asm volatile("s_waitcnt lgkmcnt(0)" ::: "memory");

    // ---- P fragments + PV --------------------------------------------------------
    bf16x8 pf[2][2];
#pragma unroll
    for (int mt = 0; mt < 2; ++mt)
#pragma unroll
      for (int kk = 0; kk < 2; ++kk)
        pf[mt][kk] = *(const bf16x8*)&Plds[wave][mt * 16 + col][(((kk * 4 + quad) ^ (col & 7))) * 8];
#pragma unroll
    for (int kk = 0; kk < 2; ++kk)
#pragma unroll
      for (int dt = 0; dt < 8; ++dt) {
        bf16x8 vf = *(const bf16x8*)&Vs[dt * 16 + col][(((kk * 4 + quad) ^ (col & 7))) * 8];
#pragma unroll
        for (int mt = 0; mt < 2; ++mt)
          o[mt][dt] = __builtin_amdgcn_mfma_f32_16x16x32_bf16(pf[mt][kk], vf, o[mt][dt], 0, 0, 0);
      }
    __syncthreads();   // Ks/Vs fully consumed before next staging
  }

  // ---- epilogue: normalize + store ctx bf16 (b, s, h, d) --------------------------
  float inv[2][4];
#pragma unroll
  for (int mt = 0; mt < 2; ++mt)
#pragma unroll
    for (int r = 0; r < 4; ++r) inv[mt][r] = 1.0f / l_r[mt][r];
#pragma unroll
  for (int mt = 0; mt < 2; ++mt)
#pragma unroll
    for (int dt = 0; dt < 8; ++dt)
#pragma unroll
      for (int r = 0; r < 4; ++r) {
        const int q = qw + mt * 16 + quad * 4 + r;
        const int d = dt * 16 + col;
        ctx[(size_t)(b * 1024 + q) * 4096 + h * 128 + d] = f2bf(o[mt][dt][r] * inv[mt][r]);
      }
}

// ----------------------------------------------------------------------------------
extern "C" void kernel_launch(void* const* d_in, const int* in_sizes, int n_in,
                              void* d_out, int out_size, void* d_ws, size_t ws_size,
                              hipStream_t stream) {
  const float* x    = (const float*)d_in[0];
  const float* kc   = (const float*)d_in[1];
  const float* vc   = (const float*)d_in[2];
  const float* rope = (const float*)d_in[3];
  const float* Wq   = (const float*)d_in[4];
  const float* Wk   = (const float*)d_in[5];
  const float* Wv   = (const float*)d_in[6];
  const float* Wo   = (const float*)d_in[7];

  float* out = (float*)d_out;                 // (2,1024,4096)
  float* xk  = out + 8388608;                 // (2,32,2048,128)
  float* xv  = out + 25165824;                // (2,32,2048,128)

  char* ws = (char*)d_ws;
  u16*   Xb   = (u16*)(ws + 0);               // x bf16                16,777,216 B
  u16*   Wc   = (u16*)(ws + 16777216);        // Wqkv bf16 [16.7M,117.4M)
  u16*   VTb  = (u16*)(ws + 50331648);        //   after GEMM1: V^T bf16 (overlaps Wk ok)
  u16*   Wob  = (u16*)(ws + 117440512);       // Wo bf16   [117.4M,151.0M)
  u16*   ctxb = (u16*)(ws + 150994944);       // ctx bf16  [151.0M,184.5M)
  u16*   KbB  = (u16*)(ws + 184549376);       // K bf16 (b,h,2048,128) [184.5M,218.1M)
  u16*   Qbb  = (u16*)(ws + 218103808);       // Q bf16 (b,h,1024,128), scale folded

  cvt_f32_bf16<<<8192, 256, 0, stream>>>(x, Xb, 8388608);
  cvt3_w<<<49152, 256, 0, stream>>>(Wq, Wk, Wv, Wc);
  gemm_qkv<<<dim3(48, 8), 512, 0, stream>>>(Xb, Wc, rope, Qbb, xk, KbB, xv,
                                            2048, 12288, 4096);
  cache_copy_kernel<<<32768, 256, 0, stream>>>(kc, vc, xk, xv, KbB);
  transpose_v_kernel<<<dim3(64, 4, 64), 256, 0, stream>>>(xv, VTb);
  cvt_f32_bf16<<<16384, 256, 0, stream>>>(Wo, Wob, 16777216);
  attn_kernel<<<dim3(8, 64), 256, 0, stream>>>(Qbb, KbB, VTb, ctxb);
  gemm_bt<<<dim3(32, 16), 256, 0, stream>>>(ctxb, Wob, out, 2048, 4096, 4096);
}